// Round 4
// baseline (361.491 us; speedup 1.0000x reference)
//
#include <hip/hip_runtime.h>

#define NPB  16     // dense points per block (einsum kernels)
#define KNN  16     // neighbors
#define CIN  128
#define CF   160    // Cin + PE
#define MM   16     // weightnet out channels
#define PEC  32     // positional encoding channels
#define COUT 128
#define KDIM 2560   // CF * MM
#define LEPS 1e-5f

typedef __bf16 bf16x8 __attribute__((ext_vector_type(8)));
typedef float  f32x4  __attribute__((ext_vector_type(4)));
union U16x8 { uint4 u4; bf16x8 b; unsigned short us[8]; };

// LDS weight-bank offsets (floats)
#define SW_PE_W0   0
#define SW_PE_B0   96
#define SW_PE_G0   128
#define SW_PE_BE0  160
#define SW_PE_W1   192
#define SW_PE_B1   1216
#define SW_PE_G1   1248
#define SW_PE_BE1  1280
#define SW_WN_W0   1312
#define SW_WN_B0   1360
#define SW_WN_G0   1376
#define SW_WN_BE0  1392
#define SW_WN_W1   1408
#define SW_WN_B1   1664
#define SW_WN_G1   1680
#define SW_WN_BE1  1696
#define SW_WN_W2   1712
#define SW_WN_B2   1968
#define SW_WN_G2   1984
#define SW_WN_BE2  2000
#define SW_TOTAL   2016

__device__ __forceinline__ float bf2f(unsigned short b){
  union { unsigned int u; float f; } x; x.u = ((unsigned int)b) << 16; return x.f;
}
__device__ __forceinline__ unsigned short f2bf(float f){
  union { float f; unsigned int u; } x; x.f = f;
  unsigned int r = (x.u + 0x7fffu + ((x.u >> 16) & 1u)) >> 16;
  return (unsigned short)r;
}
// HW RTNE convert via __bf16 cast
__device__ __forceinline__ unsigned short f2b(float f){
  union { __bf16 h; unsigned short u; } v; v.h = (__bf16)f; return v.u;
}
__device__ __forceinline__ float rsum16(float v){
  v += __shfl_xor(v, 8, 16);
  v += __shfl_xor(v, 4, 16);
  v += __shfl_xor(v, 2, 16);
  v += __shfl_xor(v, 1, 16);
  return v;
}
__device__ __forceinline__ float rsum8(float v){
  v += __shfl_xor(v, 4, 8);
  v += __shfl_xor(v, 2, 8);
  v += __shfl_xor(v, 1, 8);
  return v;
}
__device__ __forceinline__ float rsum32(float v){
  v += __shfl_xor(v, 16, 32);
  v += __shfl_xor(v, 8, 32);
  v += __shfl_xor(v, 4, 32);
  v += __shfl_xor(v, 2, 32);
  v += __shfl_xor(v, 1, 32);
  return v;
}
__device__ __forceinline__ float lrelu(float v){ return v >= 0.f ? v : 0.1f * v; }

template<int N>
__device__ __forceinline__ void ln_inlane(float* v, const float* g, const float* be, bool act){
  float mu = 0.f;
#pragma unroll
  for (int i = 0; i < N; ++i) mu += v[i];
  mu *= (1.f / N);
  float var = 0.f;
#pragma unroll
  for (int i = 0; i < N; ++i) { float d = v[i] - mu; var += d * d; }
  const float rs = rsqrtf(var * (1.f / N) + LEPS);
#pragma unroll
  for (int i = 0; i < N; ++i) {
    float y = (v[i] - mu) * rs * g[i] + be[i];
    v[i] = act ? lrelu(y) : y;
  }
}

// ============================================================================
// Kernel PREP: blocks [0,160) pack lin_w -> wpack fragments; rest convert
// sparse_feats f32 -> bf16 (2.56 MB; fits per-XCD L2 for the gathers).
// wpack permutation (matches einsum's i' store order):
//   i' = P*512 + c16*32 + q*8 + ctl*4 + r, c = P*32 + ctl*16 + c16, m = q*4+r,
//   lin_w row = c*16 + m. Fragment (s,tt,lane,j): i' = s*32+(lane>>4)*8+j,
//   n = tt*16+(lane&15), at wpack[((s*8+tt)*64+lane)*8 + j].
// ============================================================================
__global__ __launch_bounds__(256)
void pct_prep(const float* __restrict__ lin_w, unsigned short* __restrict__ wpack,
              const float* __restrict__ sf, unsigned short* __restrict__ sfb16,
              const int n4)
{
  const int bid = blockIdx.x;
  if (bid < 160) {
    const int u    = bid * 256 + threadIdx.x;   // 0..40959
    const int lane = u & 63;
    const int tt   = (u >> 6) & 7;
    const int s    = u >> 9;
    const int ipb  = s * 32 + ((lane >> 4) * 8);
    const int nn   = tt * 16 + (lane & 15);
    unsigned short v[8];
#pragma unroll
    for (int j = 0; j < 8; ++j) {
      const int ip  = ipb + j;
      const int r   = ip & 3;
      const int ctl = (ip >> 2) & 1;
      const int qq  = (ip >> 3) & 3;
      const int c16 = (ip >> 5) & 15;
      const int P   = ip >> 9;
      const int c   = P * 32 + ctl * 16 + c16;
      const int m   = qq * 4 + r;
      v[j] = f2bf(lin_w[(long)(c * MM + m) * COUT + nn]);
    }
    *(uint4*)(wpack + (long)u * 8) = *(uint4*)v;
  } else {
    const int i = (bid - 160) * 256 + threadIdx.x;
    if (i >= n4) return;
    const float4 v = ((const float4*)sf)[i];
    union { unsigned short us[4]; uint2 u; } r;
    r.us[0] = f2b(v.x); r.us[1] = f2b(v.y); r.us[2] = f2b(v.z); r.us[3] = f2b(v.w);
    ((uint2*)sfb16)[i] = r.u;
  }
}

// ============================================================================
// Kernel N: per-thread small nets + fragment PACK. Fragments for point n are
// written INTO apack row n (first 768 of 2560 ushorts) -- zero extra
// workspace; einsum2 consumes them before overwriting the row.
// Per-point frag layout (ushort offsets within the row):
//   [0..256)   af  : A-frag, lanes<32, 8 ea  (wts[k=(L>>4)*8+j][m=L&15])
//   [256..512) pe0 : B-frag ct0, [l2<32][8]  (pe[k=(l2>>4)*8+j][  0+(l2&15)])
//   [512..768) pe1 : B-frag ct1, [l2<32][8]  (pe[k=(l2>>4)*8+j][ 16+(l2&15)])
// LDS 32.6 KB -> 4 blocks/CU (50% occupancy cap). Pack phase is wave-local
// (wave w computed points 4w..4w+3 and packs the same) -> 1 barrier total.
// ============================================================================
__global__ __launch_bounds__(256)
void pct_nets(
    const float* __restrict__ sparse_xyz,
    const int* __restrict__ nei_inds,
    const float* __restrict__ dense_xyz,
    const float* __restrict__ pe_w0, const float* __restrict__ pe_b0,
    const float* __restrict__ pe_g0, const float* __restrict__ pe_be0,
    const float* __restrict__ pe_w1, const float* __restrict__ pe_b1,
    const float* __restrict__ pe_g1, const float* __restrict__ pe_be1,
    const float* __restrict__ wn_w0, const float* __restrict__ wn_b0,
    const float* __restrict__ wn_g0, const float* __restrict__ wn_be0,
    const float* __restrict__ wn_w1, const float* __restrict__ wn_b1,
    const float* __restrict__ wn_g1, const float* __restrict__ wn_be1,
    const float* __restrict__ wn_w2, const float* __restrict__ wn_b2,
    const float* __restrict__ wn_g2, const float* __restrict__ wn_be2,
    unsigned short* __restrict__ apack)
{
  __shared__ float sw[SW_TOTAL];                               // 8064 B
  __shared__ __align__(16) unsigned short wtsf[16 * 256];      // 8 KB A-frags
  __shared__ __align__(16) unsigned short pef[16 * 512];       // 16 KB [p][k][32c]

  const int t     = threadIdx.x;
  const int nbase = blockIdx.x * NPB;

  // ---- stage net weights in LDS ----
  for (int i = t; i < 96;   i += 256) sw[SW_PE_W0 + i] = pe_w0[i];
  for (int i = t; i < 32;   i += 256) {
    sw[SW_PE_B0 + i] = pe_b0[i];  sw[SW_PE_G0 + i] = pe_g0[i];  sw[SW_PE_BE0 + i] = pe_be0[i];
    sw[SW_PE_B1 + i] = pe_b1[i];  sw[SW_PE_G1 + i] = pe_g1[i];  sw[SW_PE_BE1 + i] = pe_be1[i];
  }
  for (int i = t; i < 1024; i += 256) sw[SW_PE_W1 + i] = pe_w1[i];
  for (int i = t; i < 48;   i += 256) sw[SW_WN_W0 + i] = wn_w0[i];
  for (int i = t; i < 16;   i += 256) {
    sw[SW_WN_B0 + i] = wn_b0[i];  sw[SW_WN_G0 + i] = wn_g0[i];  sw[SW_WN_BE0 + i] = wn_be0[i];
    sw[SW_WN_B1 + i] = wn_b1[i];  sw[SW_WN_G1 + i] = wn_g1[i];  sw[SW_WN_BE1 + i] = wn_be1[i];
    sw[SW_WN_B2 + i] = wn_b2[i];  sw[SW_WN_G2 + i] = wn_g2[i];  sw[SW_WN_BE2 + i] = wn_be2[i];
  }
  for (int i = t; i < 256;  i += 256) { sw[SW_WN_W1 + i] = wn_w1[i]; sw[SW_WN_W2 + i] = wn_w2[i]; }
  __syncthreads();

  // ---- nets: thread (p = t>>4, k = t&15) ----
  {
    const int p  = t >> 4;
    const int kk = t & 15;
    const int n  = nbase + p;
    const int idx = nei_inds[n * KNN + kk];
    const float x0 = sparse_xyz[idx*3+0] - dense_xyz[n*3+0];
    const float x1 = sparse_xyz[idx*3+1] - dense_xyz[n*3+1];
    const float x2 = sparse_xyz[idx*3+2] - dense_xyz[n*3+2];

    // pe layer0 (3->32) + LN + act
    float h[32];
#pragma unroll
    for (int c = 0; c < 32; ++c)
      h[c] = x0*sw[SW_PE_W0+c] + x1*sw[SW_PE_W0+32+c] + x2*sw[SW_PE_W0+64+c] + sw[SW_PE_B0+c];
    ln_inlane<32>(h, &sw[SW_PE_G0], &sw[SW_PE_BE0], true);

    // pe layer1 (32->32) + LN (no act)
    float z[32];
#pragma unroll
    for (int c = 0; c < 32; ++c) z[c] = sw[SW_PE_B1 + c];
#pragma unroll 4
    for (int j = 0; j < 32; ++j) {
      const float hj = h[j];
#pragma unroll
      for (int c = 0; c < 32; ++c) z[c] += hj * sw[SW_PE_W1 + j*32 + c];
    }
    ln_inlane<32>(z, &sw[SW_PE_G1], &sw[SW_PE_BE1], false);
    {
      union { unsigned short us[32]; uint4 u4[4]; } zb;
#pragma unroll
      for (int c = 0; c < 32; ++c) zb.us[c] = f2b(z[c]);
      unsigned short* pp_ = pef + p*512 + kk*32;   // [p][k][32c]
#pragma unroll
      for (int j = 0; j < 4; ++j) *(uint4*)(pp_ + j*8) = zb.u4[j];
    }

    // wn layer0 (3->16) + LN + act
    float w[16];
#pragma unroll
    for (int m = 0; m < 16; ++m)
      w[m] = x0*sw[SW_WN_W0+m] + x1*sw[SW_WN_W0+16+m] + x2*sw[SW_WN_W0+32+m] + sw[SW_WN_B0+m];
    ln_inlane<16>(w, &sw[SW_WN_G0], &sw[SW_WN_BE0], true);

    // wn layer1 (16->16) + LN + act
    float z2[16];
#pragma unroll
    for (int m = 0; m < 16; ++m) z2[m] = sw[SW_WN_B1 + m];
#pragma unroll 4
    for (int j = 0; j < 16; ++j) {
      const float wj = w[j];
#pragma unroll
      for (int m = 0; m < 16; ++m) z2[m] += wj * sw[SW_WN_W1 + j*16 + m];
    }
    ln_inlane<16>(z2, &sw[SW_WN_G1], &sw[SW_WN_BE1], true);

    // wn layer2 (16->16) + LN (no act)
#pragma unroll
    for (int m = 0; m < 16; ++m) w[m] = sw[SW_WN_B2 + m];
#pragma unroll 4
    for (int j = 0; j < 16; ++j) {
      const float wj = z2[j];
#pragma unroll
      for (int m = 0; m < 16; ++m) w[m] += wj * sw[SW_WN_W2 + j*16 + m];
    }
    ln_inlane<16>(w, &sw[SW_WN_G2], &sw[SW_WN_BE2], false);
    // A-fragment store: slot lane L=(kk>>3)*16+m holds wts[k=(L>>4)*8+j][m=L&15]
    {
      unsigned short* wf = wtsf + p*256 + ((kk >> 3) << 7) + (kk & 7);
#pragma unroll
      for (int m = 0; m < 16; ++m) wf[m*8] = f2b(w[m]);
    }
  }
  // NO barrier: wave w wrote wtsf/pef for points 4w..4w+3 and packs the same.
  // (DS ops from one wave complete in order at the LDS unit.)

  // ---- pack phase: coalesced fragment stores into apack rows ----
  {
    const int lane = t & 63;
    const int wave = t >> 6;
    const int l2   = lane & 31;
    const int ct2  = lane >> 5;        // lanes<32 -> pe ct0 (+af), lanes>=32 -> pe ct1
#pragma unroll
    for (int i = 0; i < 4; ++i) {
      const int p = wave*4 + i;
      unsigned short* fw = apack + (size_t)(nbase + p) * KDIM;
      if (lane < 32) {
        const uint4 a = *(const uint4*)(wtsf + p*256 + lane*8);
        *(uint4*)(fw + lane*8) = a;
      }
      union { unsigned short us[8]; uint4 u4; } o;
#pragma unroll
      for (int j = 0; j < 8; ++j)
        o.us[j] = pef[p*512 + ((l2 >> 4)*8 + j)*32 + ct2*16 + (l2 & 15)];
      *(uint4*)(fw + 256 + ct2*256 + l2*8) = o.u4;
    }
  }
}

// ============================================================================
// Kernel E2: MFMA einsum only. LDS = stage buffers alone (32 KB) -> 4
// blocks/CU. A/pe fragments read from the apack row itself (written by
// pct_nets) as 3 coalesced b128/b128/b128 loads; the row is overwritten with
// einsum output AFTER its frag loads complete (guaranteed by the counted
// vmcnt: LF(p_i) is in the oldest group drained at iteration i's wait, and
// all stores of p_i issue after that wait).
// sched_barrier(0) at the top of each iteration pins the {LF,GLDS} issue
// groups so the 3/4/5 op counts the vmcnt math uses cannot be rescheduled.
// ============================================================================
__global__ __launch_bounds__(256, 4)
void pct_einsum2(
    const int* __restrict__ nei_inds,
    const unsigned short* __restrict__ sfb16,
    unsigned short* __restrict__ apack)
{
  __shared__ __align__(16) char stage[4 * 2 * 4096];   // 4 waves x 2 bufs x 4KB

  const int t     = threadIdx.x;
  const int nbase = blockIdx.x * NPB;
  const int lane  = t & 63;
  const int wave  = t >> 6;
  const int q     = lane >> 4;      // k-slice group (0..3); >=2 zero-padded K
  const int mq    = lane & 15;      // c16 column
  char* stw = stage + wave * 8192;

  // neighbor indices for staging (instr t4 of point i uses idx[t4*4 + q])
  int idxall[4][4];
#pragma unroll
  for (int i = 0; i < 4; ++i)
#pragma unroll
    for (int t4 = 0; t4 < 4; ++t4)
      idxall[i][t4] = nei_inds[(nbase + wave*4 + i) * KNN + t4*4 + q];

  U16x8 af[2], pe0[2], pe1[2];
  const uint4 zero4 = {0u, 0u, 0u, 0u};

#define LOADF(i_, b_) do {                                                     \
    const unsigned short* fw_ = apack + (size_t)(nbase + wave*4 + (i_)) * KDIM; \
    af[b_].u4  = (lane < 32) ? *(const uint4*)(fw_ + lane*8) : zero4;          \
    pe0[b_].u4 = *(const uint4*)(fw_ + 256 + (lane & 31)*8);                   \
    pe1[b_].u4 = *(const uint4*)(fw_ + 512 + (lane & 31)*8);                   \
  } while (0)

#define GLDS(i_, b_) do {                                                     \
    _Pragma("unroll")                                                         \
    for (int t4 = 0; t4 < 4; ++t4)                                            \
      __builtin_amdgcn_global_load_lds(                                       \
          (const void*)(sfb16 + (size_t)idxall[i_][t4] * CIN + mq * 8),       \
          (void*)(stw + (b_) * 4096 + t4 * 1024), 16, 0, 0);                  \
  } while (0)

  // prologue: frag + feat tile for point 0
  LOADF(0, 0);
  GLDS(0, 0);

  f32x4 accs[10];
#pragma unroll
  for (int i = 0; i < 4; ++i) {
    const size_t n = (size_t)(nbase + wave*4 + i);

    __builtin_amdgcn_sched_barrier(0);          // fence A_i: pin group boundary
    if (i < 3) { LOADF(i+1, (i+1)&1); GLDS(i+1, (i+1)&1); }
    // vmcnt = #ops younger than this point's {LOADF(3), GLDS(4)}:
    //  i=0: LF1+G1=7 ; i=1: S0(5)+LF2+G2=12 ; i=2: S1(5)+LF3+G3=12 ; i=3: S2=5.
    if (i == 0)      asm volatile("s_waitcnt vmcnt(7)"  ::: "memory");
    else if (i == 3) asm volatile("s_waitcnt vmcnt(5)"  ::: "memory");
    else             asm volatile("s_waitcnt vmcnt(12)" ::: "memory");
    __builtin_amdgcn_sched_barrier(0);          // fence B_i

#pragma unroll
    for (int ct = 0; ct < 10; ++ct) accs[ct] = (f32x4){0.f, 0.f, 0.f, 0.f};

    // B fragments from staged feat tile [16k][128c]; row k = (q&1)*8 + j
    const unsigned short* sb = (const unsigned short*)(stw + (i & 1) * 4096)
                               + (q & 1) * 1024 + mq;
#pragma unroll
    for (int ct = 0; ct < 8; ++ct) {
      U16x8 bf_;
#pragma unroll
      for (int j = 0; j < 8; ++j) bf_.us[j] = sb[j * CIN + ct * 16];
      accs[ct] = __builtin_amdgcn_mfma_f32_16x16x32_bf16(af[i&1].b, bf_.b, accs[ct], 0, 0, 0);
    }
    // pe ctiles straight from registers
    accs[8] = __builtin_amdgcn_mfma_f32_16x16x32_bf16(af[i&1].b, pe0[i&1].b, accs[8], 0, 0, 0);
    accs[9] = __builtin_amdgcn_mfma_f32_16x16x32_bf16(af[i&1].b, pe1[i&1].b, accs[9], 0, 0, 0);

    // store: lane holds D[m=q*4+r][c=ct*16+mq]; i' = P*512+mq*32+q*8+ctl*4+r
    unsigned short* ap = apack + n * KDIM + mq * 32 + q * 8;
#pragma unroll
    for (int P = 0; P < 5; ++P) {
      union { unsigned short us[8]; uint4 u4; } o;
#pragma unroll
      for (int r = 0; r < 4; ++r) {
        o.us[r]     = f2b(accs[2*P    ][r]);
        o.us[4 + r] = f2b(accs[2*P + 1][r]);
      }
      *(uint4*)(ap + P * 512) = o.u4;
    }
  }
#undef LOADF
#undef GLDS
}

// ============================================================================
// Kernel G: C[40000x128] = A[40000x2560] @ W. Depth-4 register prefetch,
// pinned with sched_barrier(0) fences (VGPR=128, 4 waves/SIMD).
// ============================================================================
__global__ __launch_bounds__(256, 4)
void pct_gemm32(
    const unsigned short* __restrict__ apack,
    const unsigned short* __restrict__ wpack,
    const float* __restrict__ lin_b, const float* __restrict__ lin_g,
    const float* __restrict__ lin_be, const float* __restrict__ dense_feats,
    float* __restrict__ out)
{
  __shared__ float out_s[32][132];

  const int t    = threadIdx.x;
  const int lane = t & 63;
  const int wave = t >> 6;     // 0..3 -> n-tiles 2w, 2w+1
  const int n0   = blockIdx.x * 32;

  const unsigned short* arow0 = apack + (long)(n0 + (lane & 15)) * KDIM + ((lane >> 4) * 8);
  const unsigned short* arow1 = arow0 + (long)16 * KDIM;
  const unsigned short* wp0   = wpack + ((long)(wave*2) * 64 + lane) * 8;

  f32x4 acc00 = {0.f,0.f,0.f,0.f}, acc01 = {0.f,0.f,0.f,0.f};
  f32x4 acc10 = {0.f,0.f,0.f,0.f}, acc11 = {0.f,0.f,0.f,0.f};

  U16x8 a0[4], a1[4], b0[4], b1[4];
#pragma unroll
  for (int d = 0; d < 4; ++d) {
    a0[d].u4 = *(const uint4*)(arow0 + d*32);
    a1[d].u4 = *(const uint4*)(arow1 + d*32);
    b0[d].u4 = *(const uint4*)(wp0 + (long)d*4096);
    b1[d].u4 = *(const uint4*)(wp0 + (long)d*4096 + 512);
  }

#pragma unroll 4
  for (int s = 0; s < 76; ++s) {
    const int d = s & 3;
    __builtin_amdgcn_sched_barrier(0);
    acc00 = __builtin_amdgcn_mfma_f32_16x16x32_bf16(a0[d].b, b0[d].b, acc00, 0, 0, 0);
    acc01 = __builtin_amdgcn_mfma_f32_16x16x32_bf16(a0[d].b, b1[d].b, acc01, 0, 0, 0);
    acc10 = __builtin_amdgcn_mfma_f32_16x16x32_bf16(a1[d].b, b0[d].b, acc10, 0, 0, 0);
    acc11 = __builtin_amdgcn_mfma_f32_16x16x32_bf16(a1[d].b, b1[d].b, acc11, 0, 0, 0);
    __builtin_amdgcn_sched_barrier(0);
    a0[d].u4 = *(const uint4*)(arow0 + (s+4)*32);
    a1[d].u4 = *(const uint4*)(arow1 + (s+4)*32);
    b0[d].u4 = *(const uint4*)(wp0 + (long)(s+4)*4096);
    b1[d].u4 = *(const uint4*)(wp0 + (long)(s+4)*4096 + 512);
  }
#pragma unroll
  for (int s = 76; s < 80; ++s) {
    const int d = s & 3;
    __builtin_amdgcn_sched_barrier(0);
    acc00 = __builtin_amdgcn_mfma_f32_16x16x32_bf16(a0[d].b, b0[d].b, acc00, 0, 0, 0);
    acc01 = __builtin_amdgcn_mfma_f32_16x16x32_bf16(a0[d].b, b1[d].b, acc01, 0, 0, 0);
    acc10 = __builtin_amdgcn_mfma_f32_16x16x32_bf16(a1[d].b, b0[d].b, acc10, 0, 0, 0);
    acc11 = __builtin_amdgcn_mfma_f32_16x16x32_bf16(a1[d].b, b1[d].b, acc11, 0, 0, 0);
  }
  __builtin_amdgcn_sched_barrier(0);

  {
    const int quad = lane >> 4;
    const int colb = wave*32 + (lane & 15);
#pragma unroll
    for (int r = 0; r < 4; ++r) {
      out_s[     quad*4 + r][colb     ] = acc00[r];
      out_s[     quad*4 + r][colb + 16] = acc01[r];
      out_s[16 + quad*4 + r][colb     ] = acc10[r];
      out_s[16 + quad*4 + r][colb + 16] = acc11[r];
    }
  }
  __syncthreads();

  {
    const int p  = t >> 3;
    const int l8 = t & 7;
    const int n  = n0 + p;
    float v[16];
#pragma unroll
    for (int i = 0; i < 4; ++i) {
      const int cb = (i*8 + l8) * 4;
      const float4 r  = *(const float4*)(&out_s[p][cb]);
      const float4 bb = *(const float4*)(lin_b + cb);
      v[i*4+0] = r.x + bb.x; v[i*4+1] = r.y + bb.y;
      v[i*4+2] = r.z + bb.z; v[i*4+3] = r.w + bb.w;
    }
    float sum = 0.f;
#pragma unroll
    for (int i = 0; i < 16; ++i) sum += v[i];
    const float mu = rsum8(sum) * (1.f/128.f);
    float qs = 0.f;
#pragma unroll
    for (int i = 0; i < 16; ++i) { float d = v[i] - mu; qs += d*d; }
    const float rs = rsqrtf(rsum8(qs) * (1.f/128.f) + LEPS);
#pragma unroll
    for (int i = 0; i < 4; ++i) {
      const int cb = (i*8 + l8) * 4;
      const float4 g  = *(const float4*)(lin_g  + cb);
      const float4 be = *(const float4*)(lin_be + cb);
      const float4 df = *(const float4*)(dense_feats + (long)n*COUT + cb);
      float4 y;
      y.x = lrelu((v[i*4+0]-mu)*rs*g.x + be.x) + df.x;
      y.y = lrelu((v[i*4+1]-mu)*rs*g.y + be.y) + df.y;
      y.z = lrelu((v[i*4+2]-mu)*rs*g.z + be.z) + df.z;
      y.w = lrelu((v[i*4+3]-mu)*rs*g.w + be.w) + df.w;
      *(float4*)(out + (long)n*COUT + cb) = y;
    }
  }
}

// ============================================================================
// Last-resort fallback: fully-fused kernel (used if ws_size is too small)
// ============================================================================
__global__ __launch_bounds__(256)
void pct_fused(
    const float* __restrict__ sparse_xyz,
    const float* __restrict__ sparse_feats,
    const int* __restrict__ nei_inds,
    const float* __restrict__ dense_xyz,
    const float* __restrict__ dense_feats,
    const float* __restrict__ pe_w0, const float* __restrict__ pe_b0,
    const float* __restrict__ pe_g0, const float* __restrict__ pe_be0,
    const float* __restrict__ pe_w1, const float* __restrict__ pe_b1,
    const float* __restrict__ pe_g1, const float* __restrict__ pe_be1,
    const float* __restrict__ wn_w0, const float* __restrict__ wn_b0,
    const float* __restrict__ wn_g0, const float* __restrict__ wn_be0,
    const float* __restrict__ wn_w1, const float* __restrict__ wn_b1,
    const float* __restrict__ wn_g1, const float* __restrict__ wn_be1,
    const float* __restrict__ wn_w2, const float* __restrict__ wn_b2,
    const float* __restrict__ wn_g2, const float* __restrict__ wn_be2,
    const float* __restrict__ lin_w, const float* __restrict__ lin_b,
    const float* __restrict__ lin_g, const float* __restrict__ lin_be,
    float* __restrict__ out)
{
  __shared__ __align__(16) unsigned short feat_s[KNN][CF];
  __shared__ float wts_s[KNN][MM];
  __shared__ float loc_s[KNN][3];
  __shared__ int   nei_s[KNN];
  __shared__ __align__(16) unsigned short out_tile[CF*MM][8];

  const int t  = threadIdx.x;
  const int n0 = blockIdx.x * 8;
  const int k  = t >> 4;
  const int l  = t & 15;

#pragma unroll 1
  for (int p = 0; p < 8; ++p) {
    const int n = n0 + p;
    if (t < KNN) {
      int idx = nei_inds[n*KNN + t];
      nei_s[t] = idx;
      loc_s[t][0] = sparse_xyz[idx*3+0] - dense_xyz[n*3+0];
      loc_s[t][1] = sparse_xyz[idx*3+1] - dense_xyz[n*3+1];
      loc_s[t][2] = sparse_xyz[idx*3+2] - dense_xyz[n*3+2];
    }
    __syncthreads();
    {
      const int gk = t >> 4;
      const int c8 = (t & 15) * 8;
      const float* src = sparse_feats + (long)nei_s[gk]*CIN + c8;
      const float4 va = *(const float4*)(src);
      const float4 vb = *(const float4*)(src + 4);
      unsigned short* dst = &feat_s[gk][c8];
      dst[0] = f2bf(va.x); dst[1] = f2bf(va.y); dst[2] = f2bf(va.z); dst[3] = f2bf(va.w);
      dst[4] = f2bf(vb.x); dst[5] = f2bf(vb.y); dst[6] = f2bf(vb.z); dst[7] = f2bf(vb.w);
    }
    const float x0 = loc_s[k][0], x1 = loc_s[k][1], x2 = loc_s[k][2];
    const int c0 = l, c1 = l + 16;
    float ha = x0*pe_w0[0*PEC+c0] + x1*pe_w0[1*PEC+c0] + x2*pe_w0[2*PEC+c0] + pe_b0[c0];
    float hb = x0*pe_w0[0*PEC+c1] + x1*pe_w0[1*PEC+c1] + x2*pe_w0[2*PEC+c1] + pe_b0[c1];
    {
      float mu = rsum16(ha + hb) * (1.f/32.f);
      float da = ha - mu, db = hb - mu;
      float q  = rsum16(da*da + db*db);
      float rs = rsqrtf(q*(1.f/32.f) + LEPS);
      ha = lrelu(da*rs*pe_g0[c0] + pe_be0[c0]);
      hb = lrelu(db*rs*pe_g0[c1] + pe_be0[c1]);
    }
    float za = pe_b1[c0], zb = pe_b1[c1];
#pragma unroll
    for (int j = 0; j < 16; ++j) {
      float va = __shfl(ha, j, 16);
      float vb = __shfl(hb, j, 16);
      za += va * pe_w1[j*PEC + c0] + vb * pe_w1[(j+16)*PEC + c0];
      zb += va * pe_w1[j*PEC + c1] + vb * pe_w1[(j+16)*PEC + c1];
    }
    {
      float mu = rsum16(za + zb) * (1.f/32.f);
      float da = za - mu, db = zb - mu;
      float q  = rsum16(da*da + db*db);
      float rs = rsqrtf(q*(1.f/32.f) + LEPS);
      feat_s[k][CIN + c0] = f2bf(da*rs*pe_g1[c0] + pe_be1[c0]);
      feat_s[k][CIN + c1] = f2bf(db*rs*pe_g1[c1] + pe_be1[c1]);
    }
    float w0v = x0*wn_w0[0*MM+l] + x1*wn_w0[1*MM+l] + x2*wn_w0[2*MM+l] + wn_b0[l];
    {
      float mu = rsum16(w0v) * (1.f/16.f);
      float d  = w0v - mu;
      float rs = rsqrtf(rsum16(d*d)*(1.f/16.f) + LEPS);
      w0v = lrelu(d*rs*wn_g0[l] + wn_be0[l]);
    }
    float w1v = wn_b1[l];
#pragma unroll
    for (int j = 0; j < 16; ++j)
      w1v += __shfl(w0v, j, 16) * wn_w1[j*MM + l];
    {
      float mu = rsum16(w1v) * (1.f/16.f);
      float d  = w1v - mu;
      float rs = rsqrtf(rsum16(d*d)*(1.f/16.f) + LEPS);
      w1v = lrelu(d*rs*wn_g1[l] + wn_be1[l]);
    }
    float w2v = wn_b2[l];
#pragma unroll
    for (int j = 0; j < 16; ++j)
      w2v += __shfl(w1v, j, 16) * wn_w2[j*MM + l];
    {
      float mu = rsum16(w2v) * (1.f/16.f);
      float d  = w2v - mu;
      float rs = rsqrtf(rsum16(d*d)*(1.f/16.f) + LEPS);
      w2v = d*rs*wn_g2[l] + wn_be2[l];
    }
    wts_s[k][l] = w2v;
    __syncthreads();
    {
      const int m = t & 15;
      const int g = t >> 4;
      float wv[KNN];
#pragma unroll
      for (int kk = 0; kk < KNN; ++kk) wv[kk] = wts_s[kk][m];
#pragma unroll
      for (int j = 0; j < 10; ++j) {
        const int c = g*10 + j;
        float acc = 0.f;
#pragma unroll
        for (int kk = 0; kk < KNN; ++kk)
          acc += bf2f(feat_s[kk][c]) * wv[kk];
        out_tile[c*MM + m][p] = f2bf(acc);
      }
    }
    __syncthreads();
  }
  {
    const int h  = t >> 6;
    const int o0 = (t & 63) * 2;
    float acc0[8], acc1[8];
#pragma unroll
    for (int p = 0; p < 8; ++p) { acc0[p] = 0.f; acc1[p] = 0.f; }
    const int i0 = h * 640;
    for (int i = i0; i < i0 + 640; ++i) {
      const float2 wv = *(const float2*)(lin_w + (long)i*COUT + o0);
      const float wa = wv.x;
      const float wc = wv.y;
      const uint4 r = *(const uint4*)(&out_tile[i][0]);
      const float f0 = bf2f((unsigned short)(r.x & 0xffffu));
      const float f1 = bf2f((unsigned short)(r.x >> 16));
      const float g2 = bf2f((unsigned short)(r.y & 0xffffu));
      const float g3 = bf2f((unsigned short)(r.y >> 16));
      const float g4 = bf2f((unsigned short)(r.z & 0xffffu));
      const float g5 = bf2f((unsigned short)(r.z >> 16));
      const float g6 = bf2f((unsigned short)(r.w & 0xffffu));
      const float g7 = bf2f((unsigned short)(r.w >> 16));
      acc0[0] += f0*wa; acc1[0] += f0*wc;
      acc0[1] += f1*wa; acc1[1] += f1*wc;
      acc0[2] += g2*wa; acc1[2] += g2*wc;
      acc0[3] += g3*wa; acc1[3] += g3*wc;
      acc0[4] += g4*wa; acc1[4] += g4*wc;
      acc0[5] += g5*wa; acc1[5] += g5*wc;
      acc0[6] += g6*wa; acc1[6] += g6*wc;
      acc0[7] += g7*wa; acc1[7] += g7*wc;
    }
    __syncthreads();
    float* red = (float*)&out_tile[0][0];
#pragma unroll
    for (int p = 0; p < 8; ++p) {
      red[((h*8 + p) << 7) + o0    ] = acc0[p];
      red[((h*8 + p) << 7) + o0 + 1] = acc1[p];
    }
    __syncthreads();
    const int p2 = t >> 5, l2 = t & 31;
    const int n  = n0 + p2;
    float v[4];
#pragma unroll
    for (int j = 0; j < 4; ++j) {
      const int o = l2 + (j << 5);
      float sv = red[((0*8 + p2) << 7) + o] + red[((1*8 + p2) << 7) + o]
               + red[((2*8 + p2) << 7) + o] + red[((3*8 + p2) << 7) + o];
      v[j] = sv + lin_b[o];
    }
    float mu = rsum32(v[0] + v[1] + v[2] + v[3]) * (1.f/128.f);
    float q = 0.f;
#pragma unroll
    for (int j = 0; j < 4; ++j) { float d = v[j] - mu; q += d*d; }
    float rs = rsqrtf(rsum32(q) * (1.f/128.f) + LEPS);
#pragma unroll
    for (int j = 0; j < 4; ++j) {
      const int o = l2 + (j << 5);
      float y = (v[j] - mu) * rs * lin_g[o] + lin_be[o];
      y = lrelu(y);
      y += dense_feats[n*COUT + o];
      out[n*COUT + o] = y;
    }
  }
}

extern "C" void kernel_launch(void* const* d_in, const int* in_sizes, int n_in,
                              void* d_out, int out_size, void* d_ws, size_t ws_size,
                              hipStream_t stream) {
  const int Nd = in_sizes[2] / KNN;    // 40000
  const int Ns = in_sizes[1] / CIN;    // 10000
  const size_t a_bytes  = (size_t)Nd * KDIM * 2;       // 204.8 MB
  const size_t w_bytes  = (size_t)KDIM * COUT * 2;     // 655 KB
  const size_t f_bytes  = (size_t)Ns * CIN * 2;        // 2.56 MB
  const bool use_split = (ws_size >= a_bytes + w_bytes + f_bytes)
                         && (Nd % 32 == 0) && ((Ns * CIN) % 4 == 0);

  if (use_split) {
    unsigned short* apack = (unsigned short*)d_ws;
    unsigned short* wpack = (unsigned short*)((char*)d_ws + a_bytes);
    unsigned short* sfb16 = (unsigned short*)((char*)d_ws + a_bytes + w_bytes);

    const int n4 = Ns * CIN / 4;
    pct_prep<<<dim3(160 + (n4 + 255)/256), dim3(256), 0, stream>>>(
      (const float*)d_in[27], wpack, (const float*)d_in[1], sfb16, n4);

    pct_nets<<<dim3(Nd / NPB), dim3(256), 0, stream>>>(
      (const float*)d_in[0],  (const int*)d_in[2],  (const float*)d_in[4],
      (const float*)d_in[7],  (const float*)d_in[8],  (const float*)d_in[9],  (const float*)d_in[10],
      (const float*)d_in[11], (const float*)d_in[12], (const float*)d_in[13], (const float*)d_in[14],
      (const float*)d_in[15], (const float*)d_in[16], (const float*)d_in[17], (const float*)d_in[18],
      (const float*)d_in[19], (const float*)d_in[20], (const float*)d_in[21], (const float*)d_in[22],
      (const float*)d_in[23], (const float*)d_in[24], (const float*)d_in[25], (const float*)d_in[26],
      apack);

    pct_einsum2<<<dim3(Nd / NPB), dim3(256), 0, stream>>>(
      (const int*)d_in[2], sfb16, apack);

    pct_gemm32<<<dim3(Nd / 32), dim3(256), 0, stream>>>(
      apack, wpack,
      (const float*)d_in[28], (const float*)d_in[29], (const float*)d_in[30],
      (const float*)d_in[6], (float*)d_out);
  } else {
    pct_fused<<<dim3(Nd / 8), dim3(256), 0, stream>>>(
      (const float*)d_in[0],  (const float*)d_in[1],  (const int*)d_in[2],
      (const float*)d_in[4],  (const float*)d_in[6],
      (const float*)d_in[7],  (const float*)d_in[8],  (const float*)d_in[9],  (const float*)d_in[10],
      (const float*)d_in[11], (const float*)d_in[12], (const float*)d_in[13], (const float*)d_in[14],
      (const float*)d_in[15], (const float*)d_in[16], (const float*)d_in[17], (const float*)d_in[18],
      (const float*)d_in[19], (const float*)d_in[20], (const float*)d_in[21], (const float*)d_in[22],
      (const float*)d_in[23], (const float*)d_in[24], (const float*)d_in[25], (const float*)d_in[26],
      (const float*)d_in[27], (const float*)d_in[28], (const float*)d_in[29], (const float*)d_in[30],
      (float*)d_out);
  }
}

// Round 5
// 354.731 us; speedup vs baseline: 1.0191x; 1.0191x over previous
//
#include <hip/hip_runtime.h>

#define NPB  16     // dense points per block (einsum kernels)
#define KNN  16     // neighbors
#define CIN  128
#define CF   160    // Cin + PE
#define MM   16     // weightnet out channels
#define PEC  32     // positional encoding channels
#define COUT 128
#define KDIM 2560   // CF * MM
#define LEPS 1e-5f

typedef __bf16 bf16x8 __attribute__((ext_vector_type(8)));
typedef float  f32x4  __attribute__((ext_vector_type(4)));
union U16x8 { uint4 u4; bf16x8 b; unsigned short us[8]; };

// LDS weight-bank offsets (floats)
#define SW_PE_W0   0
#define SW_PE_B0   96
#define SW_PE_G0   128
#define SW_PE_BE0  160
#define SW_PE_W1   192
#define SW_PE_B1   1216
#define SW_PE_G1   1248
#define SW_PE_BE1  1280
#define SW_WN_W0   1312
#define SW_WN_B0   1360
#define SW_WN_G0   1376
#define SW_WN_BE0  1392
#define SW_WN_W1   1408
#define SW_WN_B1   1664
#define SW_WN_G1   1680
#define SW_WN_BE1  1696
#define SW_WN_W2   1712
#define SW_WN_B2   1968
#define SW_WN_G2   1984
#define SW_WN_BE2  2000
#define SW_TOTAL   2016

__device__ __forceinline__ float bf2f(unsigned short b){
  union { unsigned int u; float f; } x; x.u = ((unsigned int)b) << 16; return x.f;
}
__device__ __forceinline__ unsigned short f2bf(float f){
  union { float f; unsigned int u; } x; x.f = f;
  unsigned int r = (x.u + 0x7fffu + ((x.u >> 16) & 1u)) >> 16;
  return (unsigned short)r;
}
// HW RTNE convert via __bf16 cast
__device__ __forceinline__ unsigned short f2b(float f){
  union { __bf16 h; unsigned short u; } v; v.h = (__bf16)f; return v.u;
}
__device__ __forceinline__ float rsum16(float v){
  v += __shfl_xor(v, 8, 16);
  v += __shfl_xor(v, 4, 16);
  v += __shfl_xor(v, 2, 16);
  v += __shfl_xor(v, 1, 16);
  return v;
}
__device__ __forceinline__ float rsum8(float v){
  v += __shfl_xor(v, 4, 8);
  v += __shfl_xor(v, 2, 8);
  v += __shfl_xor(v, 1, 8);
  return v;
}
__device__ __forceinline__ float rsum32(float v){
  v += __shfl_xor(v, 16, 32);
  v += __shfl_xor(v, 8, 32);
  v += __shfl_xor(v, 4, 32);
  v += __shfl_xor(v, 2, 32);
  v += __shfl_xor(v, 1, 32);
  return v;
}
__device__ __forceinline__ float lrelu(float v){ return v >= 0.f ? v : 0.1f * v; }

template<int N>
__device__ __forceinline__ void ln_inlane(float* v, const float* g, const float* be, bool act){
  float mu = 0.f;
#pragma unroll
  for (int i = 0; i < N; ++i) mu += v[i];
  mu *= (1.f / N);
  float var = 0.f;
#pragma unroll
  for (int i = 0; i < N; ++i) { float d = v[i] - mu; var += d * d; }
  const float rs = rsqrtf(var * (1.f / N) + LEPS);
#pragma unroll
  for (int i = 0; i < N; ++i) {
    float y = (v[i] - mu) * rs * g[i] + be[i];
    v[i] = act ? lrelu(y) : y;
  }
}

// ============================================================================
// Kernel PREP: blocks [0,160) pack lin_w -> wpack fragments; rest convert
// sparse_feats f32 -> bf16 (2.56 MB; fits per-XCD L2 for the gathers).
// wpack permutation (matches einsum's i' store order):
//   i' = P*512 + c16*32 + q*8 + ctl*4 + r, c = P*32 + ctl*16 + c16, m = q*4+r,
//   lin_w row = c*16 + m. Fragment (s,tt,lane,j): i' = s*32+(lane>>4)*8+j,
//   n = tt*16+(lane&15), at wpack[((s*8+tt)*64+lane)*8 + j].
// ============================================================================
__global__ __launch_bounds__(256)
void pct_prep(const float* __restrict__ lin_w, unsigned short* __restrict__ wpack,
              const float* __restrict__ sf, unsigned short* __restrict__ sfb16,
              const int n4)
{
  const int bid = blockIdx.x;
  if (bid < 160) {
    const int u    = bid * 256 + threadIdx.x;   // 0..40959
    const int lane = u & 63;
    const int tt   = (u >> 6) & 7;
    const int s    = u >> 9;
    const int ipb  = s * 32 + ((lane >> 4) * 8);
    const int nn   = tt * 16 + (lane & 15);
    unsigned short v[8];
#pragma unroll
    for (int j = 0; j < 8; ++j) {
      const int ip  = ipb + j;
      const int r   = ip & 3;
      const int ctl = (ip >> 2) & 1;
      const int qq  = (ip >> 3) & 3;
      const int c16 = (ip >> 5) & 15;
      const int P   = ip >> 9;
      const int c   = P * 32 + ctl * 16 + c16;
      const int m   = qq * 4 + r;
      v[j] = f2bf(lin_w[(long)(c * MM + m) * COUT + nn]);
    }
    *(uint4*)(wpack + (long)u * 8) = *(uint4*)v;
  } else {
    const int i = (bid - 160) * 256 + threadIdx.x;
    if (i >= n4) return;
    const float4 v = ((const float4*)sf)[i];
    union { unsigned short us[4]; uint2 u; } r;
    r.us[0] = f2b(v.x); r.us[1] = f2b(v.y); r.us[2] = f2b(v.z); r.us[3] = f2b(v.w);
    ((uint2*)sfb16)[i] = r.u;
  }
}

// ============================================================================
// Kernel N: per-thread small nets + fragment PACK. Fragments for point n are
// written INTO apack row n (first 768 of 2560 ushorts) -- zero extra
// workspace; einsum2 consumes them before overwriting the row.
// Per-point frag layout (ushort offsets within the row):
//   [0..256)   af  : A-frag, lanes<32, 8 ea  (wts[k=(L>>4)*8+j][m=L&15])
//   [256..512) pe0 : B-frag ct0, [l2<32][8]  (pe[k=(l2>>4)*8+j][  0+(l2&15)])
//   [512..768) pe1 : B-frag ct1, [l2<32][8]  (pe[k=(l2>>4)*8+j][ 16+(l2&15)])
// ============================================================================
__global__ __launch_bounds__(256)
void pct_nets(
    const float* __restrict__ sparse_xyz,
    const int* __restrict__ nei_inds,
    const float* __restrict__ dense_xyz,
    const float* __restrict__ pe_w0, const float* __restrict__ pe_b0,
    const float* __restrict__ pe_g0, const float* __restrict__ pe_be0,
    const float* __restrict__ pe_w1, const float* __restrict__ pe_b1,
    const float* __restrict__ pe_g1, const float* __restrict__ pe_be1,
    const float* __restrict__ wn_w0, const float* __restrict__ wn_b0,
    const float* __restrict__ wn_g0, const float* __restrict__ wn_be0,
    const float* __restrict__ wn_w1, const float* __restrict__ wn_b1,
    const float* __restrict__ wn_g1, const float* __restrict__ wn_be1,
    const float* __restrict__ wn_w2, const float* __restrict__ wn_b2,
    const float* __restrict__ wn_g2, const float* __restrict__ wn_be2,
    unsigned short* __restrict__ apack)
{
  __shared__ float sw[SW_TOTAL];                               // 8064 B
  __shared__ __align__(16) unsigned short wtsf[16 * 256];      // 8 KB A-frags
  __shared__ __align__(16) unsigned short pef[16 * 512];       // 16 KB [p][k][32c]

  const int t     = threadIdx.x;
  const int nbase = blockIdx.x * NPB;

  // ---- stage net weights in LDS ----
  for (int i = t; i < 96;   i += 256) sw[SW_PE_W0 + i] = pe_w0[i];
  for (int i = t; i < 32;   i += 256) {
    sw[SW_PE_B0 + i] = pe_b0[i];  sw[SW_PE_G0 + i] = pe_g0[i];  sw[SW_PE_BE0 + i] = pe_be0[i];
    sw[SW_PE_B1 + i] = pe_b1[i];  sw[SW_PE_G1 + i] = pe_g1[i];  sw[SW_PE_BE1 + i] = pe_be1[i];
  }
  for (int i = t; i < 1024; i += 256) sw[SW_PE_W1 + i] = pe_w1[i];
  for (int i = t; i < 48;   i += 256) sw[SW_WN_W0 + i] = wn_w0[i];
  for (int i = t; i < 16;   i += 256) {
    sw[SW_WN_B0 + i] = wn_b0[i];  sw[SW_WN_G0 + i] = wn_g0[i];  sw[SW_WN_BE0 + i] = wn_be0[i];
    sw[SW_WN_B1 + i] = wn_b1[i];  sw[SW_WN_G1 + i] = wn_g1[i];  sw[SW_WN_BE1 + i] = wn_be1[i];
    sw[SW_WN_B2 + i] = wn_b2[i];  sw[SW_WN_G2 + i] = wn_g2[i];  sw[SW_WN_BE2 + i] = wn_be2[i];
  }
  for (int i = t; i < 256;  i += 256) { sw[SW_WN_W1 + i] = wn_w1[i]; sw[SW_WN_W2 + i] = wn_w2[i]; }
  __syncthreads();

  // ---- nets: thread (p = t>>4, k = t&15) ----
  {
    const int p  = t >> 4;
    const int kk = t & 15;
    const int n  = nbase + p;
    const int idx = nei_inds[n * KNN + kk];
    const float x0 = sparse_xyz[idx*3+0] - dense_xyz[n*3+0];
    const float x1 = sparse_xyz[idx*3+1] - dense_xyz[n*3+1];
    const float x2 = sparse_xyz[idx*3+2] - dense_xyz[n*3+2];

    // pe layer0 (3->32) + LN + act
    float h[32];
#pragma unroll
    for (int c = 0; c < 32; ++c)
      h[c] = x0*sw[SW_PE_W0+c] + x1*sw[SW_PE_W0+32+c] + x2*sw[SW_PE_W0+64+c] + sw[SW_PE_B0+c];
    ln_inlane<32>(h, &sw[SW_PE_G0], &sw[SW_PE_BE0], true);

    // pe layer1 (32->32) + LN (no act)
    float z[32];
#pragma unroll
    for (int c = 0; c < 32; ++c) z[c] = sw[SW_PE_B1 + c];
#pragma unroll 4
    for (int j = 0; j < 32; ++j) {
      const float hj = h[j];
#pragma unroll
      for (int c = 0; c < 32; ++c) z[c] += hj * sw[SW_PE_W1 + j*32 + c];
    }
    ln_inlane<32>(z, &sw[SW_PE_G1], &sw[SW_PE_BE1], false);
    {
      union { unsigned short us[32]; uint4 u4[4]; } zb;
#pragma unroll
      for (int c = 0; c < 32; ++c) zb.us[c] = f2b(z[c]);
      unsigned short* pp_ = pef + p*512 + kk*32;   // [p][k][32c]
#pragma unroll
      for (int j = 0; j < 4; ++j) *(uint4*)(pp_ + j*8) = zb.u4[j];
    }

    // wn layer0 (3->16) + LN + act
    float w[16];
#pragma unroll
    for (int m = 0; m < 16; ++m)
      w[m] = x0*sw[SW_WN_W0+m] + x1*sw[SW_WN_W0+16+m] + x2*sw[SW_WN_W0+32+m] + sw[SW_WN_B0+m];
    ln_inlane<16>(w, &sw[SW_WN_G0], &sw[SW_WN_BE0], true);

    // wn layer1 (16->16) + LN + act
    float z2[16];
#pragma unroll
    for (int m = 0; m < 16; ++m) z2[m] = sw[SW_WN_B1 + m];
#pragma unroll 4
    for (int j = 0; j < 16; ++j) {
      const float wj = w[j];
#pragma unroll
      for (int m = 0; m < 16; ++m) z2[m] += wj * sw[SW_WN_W1 + j*16 + m];
    }
    ln_inlane<16>(z2, &sw[SW_WN_G1], &sw[SW_WN_BE1], true);

    // wn layer2 (16->16) + LN (no act)
#pragma unroll
    for (int m = 0; m < 16; ++m) w[m] = sw[SW_WN_B2 + m];
#pragma unroll 4
    for (int j = 0; j < 16; ++j) {
      const float wj = z2[j];
#pragma unroll
      for (int m = 0; m < 16; ++m) w[m] += wj * sw[SW_WN_W2 + j*16 + m];
    }
    ln_inlane<16>(w, &sw[SW_WN_G2], &sw[SW_WN_BE2], false);
    // A-fragment store: slot lane L=(kk>>3)*16+m holds wts[k=(L>>4)*8+j][m=L&15]
    {
      unsigned short* wf = wtsf + p*256 + ((kk >> 3) << 7) + (kk & 7);
#pragma unroll
      for (int m = 0; m < 16; ++m) wf[m*8] = f2b(w[m]);
    }
  }
  // NO barrier: wave w wrote wtsf/pef for points 4w..4w+3 and packs the same.

  // ---- pack phase: coalesced fragment stores into apack rows ----
  {
    const int lane = t & 63;
    const int wave = t >> 6;
    const int l2   = lane & 31;
    const int ct2  = lane >> 5;        // lanes<32 -> pe ct0 (+af), lanes>=32 -> pe ct1
#pragma unroll
    for (int i = 0; i < 4; ++i) {
      const int p = wave*4 + i;
      unsigned short* fw = apack + (size_t)(nbase + p) * KDIM;
      if (lane < 32) {
        const uint4 a = *(const uint4*)(wtsf + p*256 + lane*8);
        *(uint4*)(fw + lane*8) = a;
      }
      union { unsigned short us[8]; uint4 u4; } o;
#pragma unroll
      for (int j = 0; j < 8; ++j)
        o.us[j] = pef[p*512 + ((l2 >> 4)*8 + j)*32 + ct2*16 + (l2 & 15)];
      *(uint4*)(fw + 256 + ct2*256 + l2*8) = o.u4;
    }
  }
}

// ============================================================================
// Kernel E2: MFMA einsum only. LDS = stage buffers alone (32 KB) -> 4
// blocks/CU. A/pe fragments read from the apack row itself (written by
// pct_nets); row overwritten with einsum output AFTER its frag loads
// complete (counted vmcnt ordering).
// ============================================================================
__global__ __launch_bounds__(256, 4)
void pct_einsum2(
    const int* __restrict__ nei_inds,
    const unsigned short* __restrict__ sfb16,
    unsigned short* __restrict__ apack)
{
  __shared__ __align__(16) char stage[4 * 2 * 4096];   // 4 waves x 2 bufs x 4KB

  const int t     = threadIdx.x;
  const int nbase = blockIdx.x * NPB;
  const int lane  = t & 63;
  const int wave  = t >> 6;
  const int q     = lane >> 4;      // k-slice group (0..3); >=2 zero-padded K
  const int mq    = lane & 15;      // c16 column
  char* stw = stage + wave * 8192;

  // neighbor indices for staging (instr t4 of point i uses idx[t4*4 + q])
  int idxall[4][4];
#pragma unroll
  for (int i = 0; i < 4; ++i)
#pragma unroll
    for (int t4 = 0; t4 < 4; ++t4)
      idxall[i][t4] = nei_inds[(nbase + wave*4 + i) * KNN + t4*4 + q];

  U16x8 af[2], pe0[2], pe1[2];
  const uint4 zero4 = {0u, 0u, 0u, 0u};

#define LOADF(i_, b_) do {                                                     \
    const unsigned short* fw_ = apack + (size_t)(nbase + wave*4 + (i_)) * KDIM; \
    af[b_].u4  = (lane < 32) ? *(const uint4*)(fw_ + lane*8) : zero4;          \
    pe0[b_].u4 = *(const uint4*)(fw_ + 256 + (lane & 31)*8);                   \
    pe1[b_].u4 = *(const uint4*)(fw_ + 512 + (lane & 31)*8);                   \
  } while (0)

#define GLDS(i_, b_) do {                                                     \
    _Pragma("unroll")                                                         \
    for (int t4 = 0; t4 < 4; ++t4)                                            \
      __builtin_amdgcn_global_load_lds(                                       \
          (const void*)(sfb16 + (size_t)idxall[i_][t4] * CIN + mq * 8),       \
          (void*)(stw + (b_) * 4096 + t4 * 1024), 16, 0, 0);                  \
  } while (0)

  // prologue: frag + feat tile for point 0
  LOADF(0, 0);
  GLDS(0, 0);

  f32x4 accs[10];
#pragma unroll
  for (int i = 0; i < 4; ++i) {
    const size_t n = (size_t)(nbase + wave*4 + i);

    __builtin_amdgcn_sched_barrier(0);          // fence A_i: pin group boundary
    if (i < 3) { LOADF(i+1, (i+1)&1); GLDS(i+1, (i+1)&1); }
    // vmcnt = #ops younger than this point's {LOADF(3), GLDS(4)}:
    //  i=0: LF1+G1=7 ; i=1: S0(5)+LF2+G2=12 ; i=2: S1(5)+LF3+G3=12 ; i=3: S2=5.
    if (i == 0)      asm volatile("s_waitcnt vmcnt(7)"  ::: "memory");
    else if (i == 3) asm volatile("s_waitcnt vmcnt(5)"  ::: "memory");
    else             asm volatile("s_waitcnt vmcnt(12)" ::: "memory");
    __builtin_amdgcn_sched_barrier(0);          // fence B_i

#pragma unroll
    for (int ct = 0; ct < 10; ++ct) accs[ct] = (f32x4){0.f, 0.f, 0.f, 0.f};

    // B fragments from staged feat tile [16k][128c]; row k = (q&1)*8 + j
    const unsigned short* sb = (const unsigned short*)(stw + (i & 1) * 4096)
                               + (q & 1) * 1024 + mq;
#pragma unroll
    for (int ct = 0; ct < 8; ++ct) {
      U16x8 bf_;
#pragma unroll
      for (int j = 0; j < 8; ++j) bf_.us[j] = sb[j * CIN + ct * 16];
      accs[ct] = __builtin_amdgcn_mfma_f32_16x16x32_bf16(af[i&1].b, bf_.b, accs[ct], 0, 0, 0);
    }
    // pe ctiles straight from registers
    accs[8] = __builtin_amdgcn_mfma_f32_16x16x32_bf16(af[i&1].b, pe0[i&1].b, accs[8], 0, 0, 0);
    accs[9] = __builtin_amdgcn_mfma_f32_16x16x32_bf16(af[i&1].b, pe1[i&1].b, accs[9], 0, 0, 0);

    // store: lane holds D[m=q*4+r][c=ct*16+mq]; i' = P*512+mq*32+q*8+ctl*4+r
    unsigned short* ap = apack + n * KDIM + mq * 32 + q * 8;
#pragma unroll
    for (int P = 0; P < 5; ++P) {
      union { unsigned short us[8]; uint4 u4; } o;
#pragma unroll
      for (int r = 0; r < 4; ++r) {
        o.us[r]     = f2b(accs[2*P    ][r]);
        o.us[4 + r] = f2b(accs[2*P + 1][r]);
      }
      *(uint4*)(ap + P * 512) = o.u4;
    }
  }
#undef LOADF
#undef GLDS
}

// ============================================================================
// Kernel G: C[40000x128] = A[40000x2560] @ W. 32 points/block (1250 blocks).
// Round-4 post-mortem: plain C++ loads + sched_barrier fences did NOT pin
// the prefetch (VGPR=48 -> ~1 set in flight -> latency-bound, MfmaUtil 8%).
// Now: inline-asm global_load_dwordx4 (opaque to the compiler: cannot be
// sunk, no auto-waitcnt, "=v" outputs force liveness) + manual counted
// vmcnt, depth 5 (20 loads / 320 B per lane in flight). Steady state
// vmcnt(16) completes exactly the current set; tail drains 16/12/8/4/0.
// sched_barrier(0) after each waitcnt (rule: MFMA hoists past asm waits).
// WAR on recycled set regs is safe: MFMA latches operands at issue, load
// return is 100s of cycles later.
// ============================================================================
#define GL4(dst_, src_) \
  asm volatile("global_load_dwordx4 %0, %1, off" : "=v"(dst_) : "v"(src_))

__global__ __launch_bounds__(256, 4)
void pct_gemm32(
    const unsigned short* __restrict__ apack,
    const unsigned short* __restrict__ wpack,
    const float* __restrict__ lin_b, const float* __restrict__ lin_g,
    const float* __restrict__ lin_be, const float* __restrict__ dense_feats,
    float* __restrict__ out)
{
  __shared__ float out_s[32][132];

  const int t    = threadIdx.x;
  const int lane = t & 63;
  const int wave = t >> 6;     // 0..3 -> n-tiles 2w, 2w+1
  const int n0   = blockIdx.x * 32;

  const unsigned short* arow0 = apack + (long)(n0 + (lane & 15)) * KDIM + ((lane >> 4) * 8);
  const unsigned short* arow1 = arow0 + (long)16 * KDIM;
  const unsigned short* wp0   = wpack + ((long)(wave*2) * 64 + lane) * 8;

  f32x4 acc00 = {0.f,0.f,0.f,0.f}, acc01 = {0.f,0.f,0.f,0.f};
  f32x4 acc10 = {0.f,0.f,0.f,0.f}, acc11 = {0.f,0.f,0.f,0.f};

  U16x8 A0[5], A1[5], B0[5], B1[5];

  // prologue: issue sets 0..4 (20 loads in flight)
#pragma unroll
  for (int d = 0; d < 5; ++d) {
    GL4(A0[d].u4, arow0 + d*32);
    GL4(A1[d].u4, arow1 + d*32);
    GL4(B0[d].u4, wp0 + (long)d*4096);
    GL4(B1[d].u4, wp0 + (long)d*4096 + 512);
  }

  // main loop: s = 0..74 (issues for s+5), steady vmcnt(16)
#pragma unroll 1
  for (int ss = 0; ss < 15; ++ss) {
#pragma unroll
    for (int d = 0; d < 5; ++d) {
      const int s = ss*5 + d;
      asm volatile("s_waitcnt vmcnt(16)" ::: "memory");
      __builtin_amdgcn_sched_barrier(0);
      acc00 = __builtin_amdgcn_mfma_f32_16x16x32_bf16(A0[d].b, B0[d].b, acc00, 0, 0, 0);
      acc01 = __builtin_amdgcn_mfma_f32_16x16x32_bf16(A0[d].b, B1[d].b, acc01, 0, 0, 0);
      acc10 = __builtin_amdgcn_mfma_f32_16x16x32_bf16(A1[d].b, B0[d].b, acc10, 0, 0, 0);
      acc11 = __builtin_amdgcn_mfma_f32_16x16x32_bf16(A1[d].b, B1[d].b, acc11, 0, 0, 0);
      __builtin_amdgcn_sched_barrier(0);
      GL4(A0[d].u4, arow0 + (s+5)*32);
      GL4(A1[d].u4, arow1 + (s+5)*32);
      GL4(B0[d].u4, wp0 + (long)(s+5)*4096);
      GL4(B1[d].u4, wp0 + (long)(s+5)*4096 + 512);
    }
  }
  // tail: s = 75..79, no new issues; drain 16/12/8/4/0
#pragma unroll
  for (int d = 0; d < 5; ++d) {
    if (d == 0)      asm volatile("s_waitcnt vmcnt(16)" ::: "memory");
    else if (d == 1) asm volatile("s_waitcnt vmcnt(12)" ::: "memory");
    else if (d == 2) asm volatile("s_waitcnt vmcnt(8)"  ::: "memory");
    else if (d == 3) asm volatile("s_waitcnt vmcnt(4)"  ::: "memory");
    else             asm volatile("s_waitcnt vmcnt(0)"  ::: "memory");
    __builtin_amdgcn_sched_barrier(0);
    acc00 = __builtin_amdgcn_mfma_f32_16x16x32_bf16(A0[d].b, B0[d].b, acc00, 0, 0, 0);
    acc01 = __builtin_amdgcn_mfma_f32_16x16x32_bf16(A0[d].b, B1[d].b, acc01, 0, 0, 0);
    acc10 = __builtin_amdgcn_mfma_f32_16x16x32_bf16(A1[d].b, B0[d].b, acc10, 0, 0, 0);
    acc11 = __builtin_amdgcn_mfma_f32_16x16x32_bf16(A1[d].b, B1[d].b, acc11, 0, 0, 0);
  }
  __builtin_amdgcn_sched_barrier(0);

  // scatter: row = at*16 + quad*4 + r, col = wave*32 + bt*16 + (lane&15)
  {
    const int quad = lane >> 4;
    const int colb = wave*32 + (lane & 15);
#pragma unroll
    for (int r = 0; r < 4; ++r) {
      out_s[     quad*4 + r][colb     ] = acc00[r];
      out_s[     quad*4 + r][colb + 16] = acc01[r];
      out_s[16 + quad*4 + r][colb     ] = acc10[r];
      out_s[16 + quad*4 + r][colb + 16] = acc11[r];
    }
  }
  __syncthreads();

  // epilogue: 8 threads/point, 16 cols each (column-interleaved)
  {
    const int p  = t >> 3;
    const int l8 = t & 7;
    const int n  = n0 + p;
    float v[16];
#pragma unroll
    for (int i = 0; i < 4; ++i) {
      const int cb = (i*8 + l8) * 4;
      const float4 r  = *(const float4*)(&out_s[p][cb]);
      const float4 bb = *(const float4*)(lin_b + cb);
      v[i*4+0] = r.x + bb.x; v[i*4+1] = r.y + bb.y;
      v[i*4+2] = r.z + bb.z; v[i*4+3] = r.w + bb.w;
    }
    float sum = 0.f;
#pragma unroll
    for (int i = 0; i < 16; ++i) sum += v[i];
    const float mu = rsum8(sum) * (1.f/128.f);
    float qs = 0.f;
#pragma unroll
    for (int i = 0; i < 16; ++i) { float d = v[i] - mu; qs += d*d; }
    const float rs = rsqrtf(rsum8(qs) * (1.f/128.f) + LEPS);
#pragma unroll
    for (int i = 0; i < 4; ++i) {
      const int cb = (i*8 + l8) * 4;
      const float4 g  = *(const float4*)(lin_g  + cb);
      const float4 be = *(const float4*)(lin_be + cb);
      const float4 df = *(const float4*)(dense_feats + (long)n*COUT + cb);
      float4 y;
      y.x = lrelu((v[i*4+0]-mu)*rs*g.x + be.x) + df.x;
      y.y = lrelu((v[i*4+1]-mu)*rs*g.y + be.y) + df.y;
      y.z = lrelu((v[i*4+2]-mu)*rs*g.z + be.z) + df.z;
      y.w = lrelu((v[i*4+3]-mu)*rs*g.w + be.w) + df.w;
      *(float4*)(out + (long)n*COUT + cb) = y;
    }
  }
}

// ============================================================================
// Last-resort fallback: fully-fused kernel (used if ws_size is too small)
// ============================================================================
__global__ __launch_bounds__(256)
void pct_fused(
    const float* __restrict__ sparse_xyz,
    const float* __restrict__ sparse_feats,
    const int* __restrict__ nei_inds,
    const float* __restrict__ dense_xyz,
    const float* __restrict__ dense_feats,
    const float* __restrict__ pe_w0, const float* __restrict__ pe_b0,
    const float* __restrict__ pe_g0, const float* __restrict__ pe_be0,
    const float* __restrict__ pe_w1, const float* __restrict__ pe_b1,
    const float* __restrict__ pe_g1, const float* __restrict__ pe_be1,
    const float* __restrict__ wn_w0, const float* __restrict__ wn_b0,
    const float* __restrict__ wn_g0, const float* __restrict__ wn_be0,
    const float* __restrict__ wn_w1, const float* __restrict__ wn_b1,
    const float* __restrict__ wn_g1, const float* __restrict__ wn_be1,
    const float* __restrict__ wn_w2, const float* __restrict__ wn_b2,
    const float* __restrict__ wn_g2, const float* __restrict__ wn_be2,
    const float* __restrict__ lin_w, const float* __restrict__ lin_b,
    const float* __restrict__ lin_g, const float* __restrict__ lin_be,
    float* __restrict__ out)
{
  __shared__ __align__(16) unsigned short feat_s[KNN][CF];
  __shared__ float wts_s[KNN][MM];
  __shared__ float loc_s[KNN][3];
  __shared__ int   nei_s[KNN];
  __shared__ __align__(16) unsigned short out_tile[CF*MM][8];

  const int t  = threadIdx.x;
  const int n0 = blockIdx.x * 8;
  const int k  = t >> 4;
  const int l  = t & 15;

#pragma unroll 1
  for (int p = 0; p < 8; ++p) {
    const int n = n0 + p;
    if (t < KNN) {
      int idx = nei_inds[n*KNN + t];
      nei_s[t] = idx;
      loc_s[t][0] = sparse_xyz[idx*3+0] - dense_xyz[n*3+0];
      loc_s[t][1] = sparse_xyz[idx*3+1] - dense_xyz[n*3+1];
      loc_s[t][2] = sparse_xyz[idx*3+2] - dense_xyz[n*3+2];
    }
    __syncthreads();
    {
      const int gk = t >> 4;
      const int c8 = (t & 15) * 8;
      const float* src = sparse_feats + (long)nei_s[gk]*CIN + c8;
      const float4 va = *(const float4*)(src);
      const float4 vb = *(const float4*)(src + 4);
      unsigned short* dst = &feat_s[gk][c8];
      dst[0] = f2bf(va.x); dst[1] = f2bf(va.y); dst[2] = f2bf(va.z); dst[3] = f2bf(va.w);
      dst[4] = f2bf(vb.x); dst[5] = f2bf(vb.y); dst[6] = f2bf(vb.z); dst[7] = f2bf(vb.w);
    }
    const float x0 = loc_s[k][0], x1 = loc_s[k][1], x2 = loc_s[k][2];
    const int c0 = l, c1 = l + 16;
    float ha = x0*pe_w0[0*PEC+c0] + x1*pe_w0[1*PEC+c0] + x2*pe_w0[2*PEC+c0] + pe_b0[c0];
    float hb = x0*pe_w0[0*PEC+c1] + x1*pe_w0[1*PEC+c1] + x2*pe_w0[2*PEC+c1] + pe_b0[c1];
    {
      float mu = rsum16(ha + hb) * (1.f/32.f);
      float da = ha - mu, db = hb - mu;
      float q  = rsum16(da*da + db*db);
      float rs = rsqrtf(q*(1.f/32.f) + LEPS);
      ha = lrelu(da*rs*pe_g0[c0] + pe_be0[c0]);
      hb = lrelu(db*rs*pe_g0[c1] + pe_be0[c1]);
    }
    float za = pe_b1[c0], zb = pe_b1[c1];
#pragma unroll
    for (int j = 0; j < 16; ++j) {
      float va = __shfl(ha, j, 16);
      float vb = __shfl(hb, j, 16);
      za += va * pe_w1[j*PEC + c0] + vb * pe_w1[(j+16)*PEC + c0];
      zb += va * pe_w1[j*PEC + c1] + vb * pe_w1[(j+16)*PEC + c1];
    }
    {
      float mu = rsum16(za + zb) * (1.f/32.f);
      float da = za - mu, db = zb - mu;
      float q  = rsum16(da*da + db*db);
      float rs = rsqrtf(q*(1.f/32.f) + LEPS);
      feat_s[k][CIN + c0] = f2bf(da*rs*pe_g1[c0] + pe_be1[c0]);
      feat_s[k][CIN + c1] = f2bf(db*rs*pe_g1[c1] + pe_be1[c1]);
    }
    float w0v = x0*wn_w0[0*MM+l] + x1*wn_w0[1*MM+l] + x2*wn_w0[2*MM+l] + wn_b0[l];
    {
      float mu = rsum16(w0v) * (1.f/16.f);
      float d  = w0v - mu;
      float rs = rsqrtf(rsum16(d*d)*(1.f/16.f) + LEPS);
      w0v = lrelu(d*rs*wn_g0[l] + wn_be0[l]);
    }
    float w1v = wn_b1[l];
#pragma unroll
    for (int j = 0; j < 16; ++j)
      w1v += __shfl(w0v, j, 16) * wn_w1[j*MM + l];
    {
      float mu = rsum16(w1v) * (1.f/16.f);
      float d  = w1v - mu;
      float rs = rsqrtf(rsum16(d*d)*(1.f/16.f) + LEPS);
      w1v = lrelu(d*rs*wn_g1[l] + wn_be1[l]);
    }
    float w2v = wn_b2[l];
#pragma unroll
    for (int j = 0; j < 16; ++j)
      w2v += __shfl(w1v, j, 16) * wn_w2[j*MM + l];
    {
      float mu = rsum16(w2v) * (1.f/16.f);
      float d  = w2v - mu;
      float rs = rsqrtf(rsum16(d*d)*(1.f/16.f) + LEPS);
      w2v = d*rs*wn_g2[l] + wn_be2[l];
    }
    wts_s[k][l] = w2v;
    __syncthreads();
    {
      const int m = t & 15;
      const int g = t >> 4;
      float wv[KNN];
#pragma unroll
      for (int kk = 0; kk < KNN; ++kk) wv[kk] = wts_s[kk][m];
#pragma unroll
      for (int j = 0; j < 10; ++j) {
        const int c = g*10 + j;
        float acc = 0.f;
#pragma unroll
        for (int kk = 0; kk < KNN; ++kk)
          acc += bf2f(feat_s[kk][c]) * wv[kk];
        out_tile[c*MM + m][p] = f2bf(acc);
      }
    }
    __syncthreads();
  }
  {
    const int h  = t >> 6;
    const int o0 = (t & 63) * 2;
    float acc0[8], acc1[8];
#pragma unroll
    for (int p = 0; p < 8; ++p) { acc0[p] = 0.f; acc1[p] = 0.f; }
    const int i0 = h * 640;
    for (int i = i0; i < i0 + 640; ++i) {
      const float2 wv = *(const float2*)(lin_w + (long)i*COUT + o0);
      const float wa = wv.x;
      const float wc = wv.y;
      const uint4 r = *(const uint4*)(&out_tile[i][0]);
      const float f0 = bf2f((unsigned short)(r.x & 0xffffu));
      const float f1 = bf2f((unsigned short)(r.x >> 16));
      const float g2 = bf2f((unsigned short)(r.y & 0xffffu));
      const float g3 = bf2f((unsigned short)(r.y >> 16));
      const float g4 = bf2f((unsigned short)(r.z & 0xffffu));
      const float g5 = bf2f((unsigned short)(r.z >> 16));
      const float g6 = bf2f((unsigned short)(r.w & 0xffffu));
      const float g7 = bf2f((unsigned short)(r.w >> 16));
      acc0[0] += f0*wa; acc1[0] += f0*wc;
      acc0[1] += f1*wa; acc1[1] += f1*wc;
      acc0[2] += g2*wa; acc1[2] += g2*wc;
      acc0[3] += g3*wa; acc1[3] += g3*wc;
      acc0[4] += g4*wa; acc1[4] += g4*wc;
      acc0[5] += g5*wa; acc1[5] += g5*wc;
      acc0[6] += g6*wa; acc1[6] += g6*wc;
      acc0[7] += g7*wa; acc1[7] += g7*wc;
    }
    __syncthreads();
    float* red = (float*)&out_tile[0][0];
#pragma unroll
    for (int p = 0; p < 8; ++p) {
      red[((h*8 + p) << 7) + o0    ] = acc0[p];
      red[((h*8 + p) << 7) + o0 + 1] = acc1[p];
    }
    __syncthreads();
    const int p2 = t >> 5, l2 = t & 31;
    const int n  = n0 + p2;
    float v[4];
#pragma unroll
    for (int j = 0; j < 4; ++j) {
      const int o = l2 + (j << 5);
      float sv = red[((0*8 + p2) << 7) + o] + red[((1*8 + p2) << 7) + o]
               + red[((2*8 + p2) << 7) + o] + red[((3*8 + p2) << 7) + o];
      v[j] = sv + lin_b[o];
    }
    float mu = rsum32(v[0] + v[1] + v[2] + v[3]) * (1.f/128.f);
    float q = 0.f;
#pragma unroll
    for (int j = 0; j < 4; ++j) { float d = v[j] - mu; q += d*d; }
    float rs = rsqrtf(rsum32(q) * (1.f/128.f) + LEPS);
#pragma unroll
    for (int j = 0; j < 4; ++j) {
      const int o = l2 + (j << 5);
      float y = (v[j] - mu) * rs * lin_g[o] + lin_be[o];
      y = lrelu(y);
      y += dense_feats[n*COUT + o];
      out[n*COUT + o] = y;
    }
  }
}

extern "C" void kernel_launch(void* const* d_in, const int* in_sizes, int n_in,
                              void* d_out, int out_size, void* d_ws, size_t ws_size,
                              hipStream_t stream) {
  const int Nd = in_sizes[2] / KNN;    // 40000
  const int Ns = in_sizes[1] / CIN;    // 10000
  const size_t a_bytes  = (size_t)Nd * KDIM * 2;       // 204.8 MB
  const size_t w_bytes  = (size_t)KDIM * COUT * 2;     // 655 KB
  const size_t f_bytes  = (size_t)Ns * CIN * 2;        // 2.56 MB
  const bool use_split = (ws_size >= a_bytes + w_bytes + f_bytes)
                         && (Nd % 32 == 0) && ((Ns * CIN) % 4 == 0);

  if (use_split) {
    unsigned short* apack = (unsigned short*)d_ws;
    unsigned short* wpack = (unsigned short*)((char*)d_ws + a_bytes);
    unsigned short* sfb16 = (unsigned short*)((char*)d_ws + a_bytes + w_bytes);

    const int n4 = Ns * CIN / 4;
    pct_prep<<<dim3(160 + (n4 + 255)/256), dim3(256), 0, stream>>>(
      (const float*)d_in[27], wpack, (const float*)d_in[1], sfb16, n4);

    pct_nets<<<dim3(Nd / NPB), dim3(256), 0, stream>>>(
      (const float*)d_in[0],  (const int*)d_in[2],  (const float*)d_in[4],
      (const float*)d_in[7],  (const float*)d_in[8],  (const float*)d_in[9],  (const float*)d_in[10],
      (const float*)d_in[11], (const float*)d_in[12], (const float*)d_in[13], (const float*)d_in[14],
      (const float*)d_in[15], (const float*)d_in[16], (const float*)d_in[17], (const float*)d_in[18],
      (const float*)d_in[19], (const float*)d_in[20], (const float*)d_in[21], (const float*)d_in[22],
      (const float*)d_in[23], (const float*)d_in[24], (const float*)d_in[25], (const float*)d_in[26],
      apack);

    pct_einsum2<<<dim3(Nd / NPB), dim3(256), 0, stream>>>(
      (const int*)d_in[2], sfb16, apack);

    pct_gemm32<<<dim3(Nd / 32), dim3(256), 0, stream>>>(
      apack, wpack,
      (const float*)d_in[28], (const float*)d_in[29], (const float*)d_in[30],
      (const float*)d_in[6], (float*)d_out);
  } else {
    pct_fused<<<dim3(Nd / 8), dim3(256), 0, stream>>>(
      (const float*)d_in[0],  (const float*)d_in[1],  (const int*)d_in[2],
      (const float*)d_in[4],  (const float*)d_in[6],
      (const float*)d_in[7],  (const float*)d_in[8],  (const float*)d_in[9],  (const float*)d_in[10],
      (const float*)d_in[11], (const float*)d_in[12], (const float*)d_in[13], (const float*)d_in[14],
      (const float*)d_in[15], (const float*)d_in[16], (const float*)d_in[17], (const float*)d_in[18],
      (const float*)d_in[19], (const float*)d_in[20], (const float*)d_in[21], (const float*)d_in[22],
      (const float*)d_in[23], (const float*)d_in[24], (const float*)d_in[25], (const float*)d_in[26],
      (const float*)d_in[27], (const float*)d_in[28], (const float*)d_in[29], (const float*)d_in[30],
      (float*)d_out);
  }
}

// Round 6
// 328.055 us; speedup vs baseline: 1.1019x; 1.0813x over previous
//
#include <hip/hip_runtime.h>

#define NPB  16     // dense points per block (einsum kernels)
#define KNN  16     // neighbors
#define CIN  128
#define CF   160    // Cin + PE
#define MM   16     // weightnet out channels
#define PEC  32     // positional encoding channels
#define COUT 128
#define KDIM 2560   // CF * MM
#define LEPS 1e-5f

typedef __bf16 bf16x8 __attribute__((ext_vector_type(8)));
typedef float  f32x4  __attribute__((ext_vector_type(4)));
union U16x8 { uint4 u4; bf16x8 b; unsigned short us[8]; };

// LDS weight-bank offsets (floats)
#define SW_PE_W0   0
#define SW_PE_B0   96
#define SW_PE_G0   128
#define SW_PE_BE0  160
#define SW_PE_W1   192
#define SW_PE_B1   1216
#define SW_PE_G1   1248
#define SW_PE_BE1  1280
#define SW_WN_W0   1312
#define SW_WN_B0   1360
#define SW_WN_G0   1376
#define SW_WN_BE0  1392
#define SW_WN_W1   1408
#define SW_WN_B1   1664
#define SW_WN_G1   1680
#define SW_WN_BE1  1696
#define SW_WN_W2   1712
#define SW_WN_B2   1968
#define SW_WN_G2   1984
#define SW_WN_BE2  2000
#define SW_TOTAL   2016

__device__ __forceinline__ float bf2f(unsigned short b){
  union { unsigned int u; float f; } x; x.u = ((unsigned int)b) << 16; return x.f;
}
__device__ __forceinline__ unsigned short f2bf(float f){
  union { float f; unsigned int u; } x; x.f = f;
  unsigned int r = (x.u + 0x7fffu + ((x.u >> 16) & 1u)) >> 16;
  return (unsigned short)r;
}
// HW RTNE convert via __bf16 cast
__device__ __forceinline__ unsigned short f2b(float f){
  union { __bf16 h; unsigned short u; } v; v.h = (__bf16)f; return v.u;
}
__device__ __forceinline__ float rsum16(float v){
  v += __shfl_xor(v, 8, 16);
  v += __shfl_xor(v, 4, 16);
  v += __shfl_xor(v, 2, 16);
  v += __shfl_xor(v, 1, 16);
  return v;
}
__device__ __forceinline__ float rsum8(float v){
  v += __shfl_xor(v, 4, 8);
  v += __shfl_xor(v, 2, 8);
  v += __shfl_xor(v, 1, 8);
  return v;
}
__device__ __forceinline__ float rsum32(float v){
  v += __shfl_xor(v, 16, 32);
  v += __shfl_xor(v, 8, 32);
  v += __shfl_xor(v, 4, 32);
  v += __shfl_xor(v, 2, 32);
  v += __shfl_xor(v, 1, 32);
  return v;
}
__device__ __forceinline__ float lrelu(float v){ return v >= 0.f ? v : 0.1f * v; }

template<int N>
__device__ __forceinline__ void ln_inlane(float* v, const float* g, const float* be, bool act){
  float mu = 0.f;
#pragma unroll
  for (int i = 0; i < N; ++i) mu += v[i];
  mu *= (1.f / N);
  float var = 0.f;
#pragma unroll
  for (int i = 0; i < N; ++i) { float d = v[i] - mu; var += d * d; }
  const float rs = rsqrtf(var * (1.f / N) + LEPS);
#pragma unroll
  for (int i = 0; i < N; ++i) {
    float y = (v[i] - mu) * rs * g[i] + be[i];
    v[i] = act ? lrelu(y) : y;
  }
}

// ============================================================================
// Kernel PREP: blocks [0,160) pack lin_w -> wpack fragments; rest convert
// sparse_feats f32 -> bf16 (2.56 MB; fits per-XCD L2 for the gathers).
// ============================================================================
__global__ __launch_bounds__(256)
void pct_prep(const float* __restrict__ lin_w, unsigned short* __restrict__ wpack,
              const float* __restrict__ sf, unsigned short* __restrict__ sfb16,
              const int n4)
{
  const int bid = blockIdx.x;
  if (bid < 160) {
    const int u    = bid * 256 + threadIdx.x;   // 0..40959
    const int lane = u & 63;
    const int tt   = (u >> 6) & 7;
    const int s    = u >> 9;
    const int ipb  = s * 32 + ((lane >> 4) * 8);
    const int nn   = tt * 16 + (lane & 15);
    unsigned short v[8];
#pragma unroll
    for (int j = 0; j < 8; ++j) {
      const int ip  = ipb + j;
      const int r   = ip & 3;
      const int ctl = (ip >> 2) & 1;
      const int qq  = (ip >> 3) & 3;
      const int c16 = (ip >> 5) & 15;
      const int P   = ip >> 9;
      const int c   = P * 32 + ctl * 16 + c16;
      const int m   = qq * 4 + r;
      v[j] = f2bf(lin_w[(long)(c * MM + m) * COUT + nn]);
    }
    *(uint4*)(wpack + (long)u * 8) = *(uint4*)v;
  } else {
    const int i = (bid - 160) * 256 + threadIdx.x;
    if (i >= n4) return;
    const float4 v = ((const float4*)sf)[i];
    union { unsigned short us[4]; uint2 u; } r;
    r.us[0] = f2b(v.x); r.us[1] = f2b(v.y); r.us[2] = f2b(v.z); r.us[3] = f2b(v.w);
    ((uint2*)sfb16)[i] = r.u;
  }
}

// ============================================================================
// Kernel N: per-thread small nets + fragment PACK into apack rows (first 768
// of 2560 ushorts per row; einsum2 consumes before overwriting).
// ============================================================================
__global__ __launch_bounds__(256)
void pct_nets(
    const float* __restrict__ sparse_xyz,
    const int* __restrict__ nei_inds,
    const float* __restrict__ dense_xyz,
    const float* __restrict__ pe_w0, const float* __restrict__ pe_b0,
    const float* __restrict__ pe_g0, const float* __restrict__ pe_be0,
    const float* __restrict__ pe_w1, const float* __restrict__ pe_b1,
    const float* __restrict__ pe_g1, const float* __restrict__ pe_be1,
    const float* __restrict__ wn_w0, const float* __restrict__ wn_b0,
    const float* __restrict__ wn_g0, const float* __restrict__ wn_be0,
    const float* __restrict__ wn_w1, const float* __restrict__ wn_b1,
    const float* __restrict__ wn_g1, const float* __restrict__ wn_be1,
    const float* __restrict__ wn_w2, const float* __restrict__ wn_b2,
    const float* __restrict__ wn_g2, const float* __restrict__ wn_be2,
    unsigned short* __restrict__ apack)
{
  __shared__ float sw[SW_TOTAL];                               // 8064 B
  __shared__ __align__(16) unsigned short wtsf[16 * 256];      // 8 KB A-frags
  __shared__ __align__(16) unsigned short pef[16 * 512];       // 16 KB [p][k][32c]

  const int t     = threadIdx.x;
  const int nbase = blockIdx.x * NPB;

  // ---- stage net weights in LDS ----
  for (int i = t; i < 96;   i += 256) sw[SW_PE_W0 + i] = pe_w0[i];
  for (int i = t; i < 32;   i += 256) {
    sw[SW_PE_B0 + i] = pe_b0[i];  sw[SW_PE_G0 + i] = pe_g0[i];  sw[SW_PE_BE0 + i] = pe_be0[i];
    sw[SW_PE_B1 + i] = pe_b1[i];  sw[SW_PE_G1 + i] = pe_g1[i];  sw[SW_PE_BE1 + i] = pe_be1[i];
  }
  for (int i = t; i < 1024; i += 256) sw[SW_PE_W1 + i] = pe_w1[i];
  for (int i = t; i < 48;   i += 256) sw[SW_WN_W0 + i] = wn_w0[i];
  for (int i = t; i < 16;   i += 256) {
    sw[SW_WN_B0 + i] = wn_b0[i];  sw[SW_WN_G0 + i] = wn_g0[i];  sw[SW_WN_BE0 + i] = wn_be0[i];
    sw[SW_WN_B1 + i] = wn_b1[i];  sw[SW_WN_G1 + i] = wn_g1[i];  sw[SW_WN_BE1 + i] = wn_be1[i];
    sw[SW_WN_B2 + i] = wn_b2[i];  sw[SW_WN_G2 + i] = wn_g2[i];  sw[SW_WN_BE2 + i] = wn_be2[i];
  }
  for (int i = t; i < 256;  i += 256) { sw[SW_WN_W1 + i] = wn_w1[i]; sw[SW_WN_W2 + i] = wn_w2[i]; }
  __syncthreads();

  // ---- nets: thread (p = t>>4, k = t&15) ----
  {
    const int p  = t >> 4;
    const int kk = t & 15;
    const int n  = nbase + p;
    const int idx = nei_inds[n * KNN + kk];
    const float x0 = sparse_xyz[idx*3+0] - dense_xyz[n*3+0];
    const float x1 = sparse_xyz[idx*3+1] - dense_xyz[n*3+1];
    const float x2 = sparse_xyz[idx*3+2] - dense_xyz[n*3+2];

    // pe layer0 (3->32) + LN + act
    float h[32];
#pragma unroll
    for (int c = 0; c < 32; ++c)
      h[c] = x0*sw[SW_PE_W0+c] + x1*sw[SW_PE_W0+32+c] + x2*sw[SW_PE_W0+64+c] + sw[SW_PE_B0+c];
    ln_inlane<32>(h, &sw[SW_PE_G0], &sw[SW_PE_BE0], true);

    // pe layer1 (32->32) + LN (no act)
    float z[32];
#pragma unroll
    for (int c = 0; c < 32; ++c) z[c] = sw[SW_PE_B1 + c];
#pragma unroll 4
    for (int j = 0; j < 32; ++j) {
      const float hj = h[j];
#pragma unroll
      for (int c = 0; c < 32; ++c) z[c] += hj * sw[SW_PE_W1 + j*32 + c];
    }
    ln_inlane<32>(z, &sw[SW_PE_G1], &sw[SW_PE_BE1], false);
    {
      union { unsigned short us[32]; uint4 u4[4]; } zb;
#pragma unroll
      for (int c = 0; c < 32; ++c) zb.us[c] = f2b(z[c]);
      unsigned short* pp_ = pef + p*512 + kk*32;   // [p][k][32c]
#pragma unroll
      for (int j = 0; j < 4; ++j) *(uint4*)(pp_ + j*8) = zb.u4[j];
    }

    // wn layer0 (3->16) + LN + act
    float w[16];
#pragma unroll
    for (int m = 0; m < 16; ++m)
      w[m] = x0*sw[SW_WN_W0+m] + x1*sw[SW_WN_W0+16+m] + x2*sw[SW_WN_W0+32+m] + sw[SW_WN_B0+m];
    ln_inlane<16>(w, &sw[SW_WN_G0], &sw[SW_WN_BE0], true);

    // wn layer1 (16->16) + LN + act
    float z2[16];
#pragma unroll
    for (int m = 0; m < 16; ++m) z2[m] = sw[SW_WN_B1 + m];
#pragma unroll 4
    for (int j = 0; j < 16; ++j) {
      const float wj = w[j];
#pragma unroll
      for (int m = 0; m < 16; ++m) z2[m] += wj * sw[SW_WN_W1 + j*16 + m];
    }
    ln_inlane<16>(z2, &sw[SW_WN_G1], &sw[SW_WN_BE1], true);

    // wn layer2 (16->16) + LN (no act)
#pragma unroll
    for (int m = 0; m < 16; ++m) w[m] = sw[SW_WN_B2 + m];
#pragma unroll 4
    for (int j = 0; j < 16; ++j) {
      const float wj = z2[j];
#pragma unroll
      for (int m = 0; m < 16; ++m) w[m] += wj * sw[SW_WN_W2 + j*16 + m];
    }
    ln_inlane<16>(w, &sw[SW_WN_G2], &sw[SW_WN_BE2], false);
    // A-fragment store: slot lane L=(kk>>3)*16+m holds wts[k=(L>>4)*8+j][m=L&15]
    {
      unsigned short* wf = wtsf + p*256 + ((kk >> 3) << 7) + (kk & 7);
#pragma unroll
      for (int m = 0; m < 16; ++m) wf[m*8] = f2b(w[m]);
    }
  }
  // NO barrier: wave w wrote wtsf/pef for points 4w..4w+3 and packs the same.

  // ---- pack phase: coalesced fragment stores into apack rows ----
  {
    const int lane = t & 63;
    const int wave = t >> 6;
    const int l2   = lane & 31;
    const int ct2  = lane >> 5;        // lanes<32 -> pe ct0 (+af), lanes>=32 -> pe ct1
#pragma unroll
    for (int i = 0; i < 4; ++i) {
      const int p = wave*4 + i;
      unsigned short* fw = apack + (size_t)(nbase + p) * KDIM;
      if (lane < 32) {
        const uint4 a = *(const uint4*)(wtsf + p*256 + lane*8);
        *(uint4*)(fw + lane*8) = a;
      }
      union { unsigned short us[8]; uint4 u4; } o;
#pragma unroll
      for (int j = 0; j < 8; ++j)
        o.us[j] = pef[p*512 + ((l2 >> 4)*8 + j)*32 + ct2*16 + (l2 & 15)];
      *(uint4*)(fw + 256 + ct2*256 + l2*8) = o.u4;
    }
  }
}

// ============================================================================
// Kernel E2: MFMA einsum only (unchanged from round 4).
// ============================================================================
__global__ __launch_bounds__(256, 4)
void pct_einsum2(
    const int* __restrict__ nei_inds,
    const unsigned short* __restrict__ sfb16,
    unsigned short* __restrict__ apack)
{
  __shared__ __align__(16) char stage[4 * 2 * 4096];   // 4 waves x 2 bufs x 4KB

  const int t     = threadIdx.x;
  const int nbase = blockIdx.x * NPB;
  const int lane  = t & 63;
  const int wave  = t >> 6;
  const int q     = lane >> 4;      // k-slice group (0..3); >=2 zero-padded K
  const int mq    = lane & 15;      // c16 column
  char* stw = stage + wave * 8192;

  // neighbor indices for staging (instr t4 of point i uses idx[t4*4 + q])
  int idxall[4][4];
#pragma unroll
  for (int i = 0; i < 4; ++i)
#pragma unroll
    for (int t4 = 0; t4 < 4; ++t4)
      idxall[i][t4] = nei_inds[(nbase + wave*4 + i) * KNN + t4*4 + q];

  U16x8 af[2], pe0[2], pe1[2];
  const uint4 zero4 = {0u, 0u, 0u, 0u};

#define LOADF(i_, b_) do {                                                     \
    const unsigned short* fw_ = apack + (size_t)(nbase + wave*4 + (i_)) * KDIM; \
    af[b_].u4  = (lane < 32) ? *(const uint4*)(fw_ + lane*8) : zero4;          \
    pe0[b_].u4 = *(const uint4*)(fw_ + 256 + (lane & 31)*8);                   \
    pe1[b_].u4 = *(const uint4*)(fw_ + 512 + (lane & 31)*8);                   \
  } while (0)

#define GLDS(i_, b_) do {                                                     \
    _Pragma("unroll")                                                         \
    for (int t4 = 0; t4 < 4; ++t4)                                            \
      __builtin_amdgcn_global_load_lds(                                       \
          (const void*)(sfb16 + (size_t)idxall[i_][t4] * CIN + mq * 8),       \
          (void*)(stw + (b_) * 4096 + t4 * 1024), 16, 0, 0);                  \
  } while (0)

  // prologue: frag + feat tile for point 0
  LOADF(0, 0);
  GLDS(0, 0);

  f32x4 accs[10];
#pragma unroll
  for (int i = 0; i < 4; ++i) {
    const size_t n = (size_t)(nbase + wave*4 + i);

    __builtin_amdgcn_sched_barrier(0);          // fence A_i: pin group boundary
    if (i < 3) { LOADF(i+1, (i+1)&1); GLDS(i+1, (i+1)&1); }
    // vmcnt = #ops younger than this point's {LOADF(3), GLDS(4)}:
    //  i=0: LF1+G1=7 ; i=1: S0(5)+LF2+G2=12 ; i=2: S1(5)+LF3+G3=12 ; i=3: S2=5.
    if (i == 0)      asm volatile("s_waitcnt vmcnt(7)"  ::: "memory");
    else if (i == 3) asm volatile("s_waitcnt vmcnt(5)"  ::: "memory");
    else             asm volatile("s_waitcnt vmcnt(12)" ::: "memory");
    __builtin_amdgcn_sched_barrier(0);          // fence B_i

#pragma unroll
    for (int ct = 0; ct < 10; ++ct) accs[ct] = (f32x4){0.f, 0.f, 0.f, 0.f};

    // B fragments from staged feat tile [16k][128c]; row k = (q&1)*8 + j
    const unsigned short* sb = (const unsigned short*)(stw + (i & 1) * 4096)
                               + (q & 1) * 1024 + mq;
#pragma unroll
    for (int ct = 0; ct < 8; ++ct) {
      U16x8 bf_;
#pragma unroll
      for (int j = 0; j < 8; ++j) bf_.us[j] = sb[j * CIN + ct * 16];
      accs[ct] = __builtin_amdgcn_mfma_f32_16x16x32_bf16(af[i&1].b, bf_.b, accs[ct], 0, 0, 0);
    }
    // pe ctiles straight from registers
    accs[8] = __builtin_amdgcn_mfma_f32_16x16x32_bf16(af[i&1].b, pe0[i&1].b, accs[8], 0, 0, 0);
    accs[9] = __builtin_amdgcn_mfma_f32_16x16x32_bf16(af[i&1].b, pe1[i&1].b, accs[9], 0, 0, 0);

    // store: lane holds D[m=q*4+r][c=ct*16+mq]; i' = P*512+mq*32+q*8+ctl*4+r
    unsigned short* ap = apack + n * KDIM + mq * 32 + q * 8;
#pragma unroll
    for (int P = 0; P < 5; ++P) {
      union { unsigned short us[8]; uint4 u4; } o;
#pragma unroll
      for (int r = 0; r < 4; ++r) {
        o.us[r]     = f2b(accs[2*P    ][r]);
        o.us[4 + r] = f2b(accs[2*P + 1][r]);
      }
      *(uint4*)(ap + P * 512) = o.u4;
    }
  }
#undef LOADF
#undef GLDS
}

// ============================================================================
// Kernel G v5: C[40000x128] = A[40000x2560] @ W. 32 rows/block, 1250 blocks.
// Rounds 3+4 post-mortem: register-resident A/B prefetch is destroyed by the
// compiler (sunk loads r3: VGPR=48; strangled asm outputs r4: VGPR=56, dur
// unchanged). This version stages A via WAVE-PRIVATE global_load_lds chunk
// double-buffering (in-flight state lives in vmcnt, not registers — the
// einsum2-proven pattern), with counted vmcnt(4) and NO barriers in the main
// loop. Retiling: wave w owns rows (w&1)*16..+15 and col-tiles (w>>1)*4..+3,
// so its A-tile is private. A ds_reads use an XOR slot-swizzle (source-side
// pre-swizzle, linear LDS dest): read conflicts 2-way = free. B = direct
// L2-hit loads inside the chunk (ordered after the wait by asm memory
// clobber). LDS: abuf 32 KB union-aliased over the epilogue out_s.
// ============================================================================
__global__ __launch_bounds__(256)
void pct_gemm32(
    const unsigned short* __restrict__ apack,
    const unsigned short* __restrict__ wpack,
    const float* __restrict__ lin_b, const float* __restrict__ lin_g,
    const float* __restrict__ lin_be, const float* __restrict__ dense_feats,
    float* __restrict__ out)
{
  __shared__ __align__(16) union ShU {
    char  abuf[4][2][4096];   // [wave][buf][16 rows x 256B], XOR-swizzled slots
    float outs[32][132];      // epilogue tile (aliased; barrier-separated)
  } sh;

  const int t    = threadIdx.x;
  const int lane = t & 63;
  const int wave = t >> 6;
  const int n0   = blockIdx.x * 32;

  const int q      = lane >> 4;        // 0..3 (k-slice group / staged row sub)
  const int mq     = lane & 15;        // slot (stage) / local row (read)
  const int r0     = (wave & 1) * 16;  // row-tile base
  const int ttbase = (wave >> 1) * 4;  // col-tile base (4 tiles per wave)

  char* wb = sh.abuf[wave][0];

  f32x4 acc0 = {0.f,0.f,0.f,0.f}, acc1 = {0.f,0.f,0.f,0.f};
  f32x4 acc2 = {0.f,0.f,0.f,0.f}, acc3 = {0.f,0.f,0.f,0.f};

  // Stage chunk c (4 s-steps = 256B/row) into buffer b: 4 global_load_lds.
  // LDS slot t of local row lr holds source slot (t ^ (lr&7)) — source
  // pre-swizzled, dest linear (both-sides-or-neither rule).
#define STAGEC(c_, b_) do {                                                   \
    _Pragma("unroll")                                                         \
    for (int a_ = 0; a_ < 4; ++a_) {                                          \
      const int lr_ = 4*a_ + q;                                               \
      const unsigned short* src_ = apack + (size_t)(n0 + r0 + lr_) * KDIM     \
                                 + (c_)*128 + ((mq ^ (lr_ & 7)) * 8);         \
      __builtin_amdgcn_global_load_lds((const void*)src_,                     \
          (void*)(wb + (b_)*4096 + a_*1024), 16, 0, 0);                       \
    }                                                                         \
  } while (0)

#define CHUNK(c_, b_) do {                                                    \
    _Pragma("unroll")                                                         \
    for (int s_ = 0; s_ < 4; ++s_) {                                          \
      const int sg_ = (c_)*4 + s_;                                            \
      U16x8 afr_;                                                             \
      const unsigned short* ar_ = (const unsigned short*)(wb + (b_)*4096)     \
          + mq*128 + (((s_*4 + q) ^ (mq & 7)) * 8);                           \
      afr_.u4 = *(const uint4*)ar_;                                           \
      const unsigned short* wpb_ = wpack + (size_t)sg_*4096 + ttbase*512 + lane*8; \
      U16x8 b0_, b1_, b2_, b3_;                                               \
      b0_.u4 = *(const uint4*)(wpb_);                                         \
      b1_.u4 = *(const uint4*)(wpb_ + 512);                                   \
      b2_.u4 = *(const uint4*)(wpb_ + 1024);                                  \
      b3_.u4 = *(const uint4*)(wpb_ + 1536);                                  \
      acc0 = __builtin_amdgcn_mfma_f32_16x16x32_bf16(afr_.b, b0_.b, acc0, 0,0,0); \
      acc1 = __builtin_amdgcn_mfma_f32_16x16x32_bf16(afr_.b, b1_.b, acc1, 0,0,0); \
      acc2 = __builtin_amdgcn_mfma_f32_16x16x32_bf16(afr_.b, b2_.b, acc2, 0,0,0); \
      acc3 = __builtin_amdgcn_mfma_f32_16x16x32_bf16(afr_.b, b3_.b, acc3, 0,0,0); \
    }                                                                         \
  } while (0)

  STAGEC(0, 0);
#pragma unroll 1
  for (int c = 0; c < 19; ++c) {
    STAGEC(c+1, (c+1)&1);
    // outstanding: STAGE(c)[4, oldest] (+any compiler B loads, younger,
    // already drained by its own waits) + STAGE(c+1)[4, newest] ->
    // vmcnt(4) completes STAGE(c), leaves the prefetch in flight.
    asm volatile("s_waitcnt vmcnt(4)" ::: "memory");
    __builtin_amdgcn_sched_barrier(0);
    CHUNK(c, c & 1);
  }
  asm volatile("s_waitcnt vmcnt(0)" ::: "memory");
  __builtin_amdgcn_sched_barrier(0);
  CHUNK(19, 1);
#undef STAGEC
#undef CHUNK

  __syncthreads();   // all waves done reading abuf before outs (aliased) writes

  // scatter: wave w tile j -> rows r0+q*4+r, col (ttbase+j)*16 + mq
  {
#pragma unroll
    for (int r = 0; r < 4; ++r) {
      sh.outs[r0 + q*4 + r][(ttbase+0)*16 + mq] = acc0[r];
      sh.outs[r0 + q*4 + r][(ttbase+1)*16 + mq] = acc1[r];
      sh.outs[r0 + q*4 + r][(ttbase+2)*16 + mq] = acc2[r];
      sh.outs[r0 + q*4 + r][(ttbase+3)*16 + mq] = acc3[r];
    }
  }
  __syncthreads();

  // epilogue: 8 threads/point, 16 cols each (column-interleaved)
  {
    const int p  = t >> 3;
    const int l8 = t & 7;
    const int n  = n0 + p;
    float v[16];
#pragma unroll
    for (int i = 0; i < 4; ++i) {
      const int cb = (i*8 + l8) * 4;
      const float4 r  = *(const float4*)(&sh.outs[p][cb]);
      const float4 bb = *(const float4*)(lin_b + cb);
      v[i*4+0] = r.x + bb.x; v[i*4+1] = r.y + bb.y;
      v[i*4+2] = r.z + bb.z; v[i*4+3] = r.w + bb.w;
    }
    float sum = 0.f;
#pragma unroll
    for (int i = 0; i < 16; ++i) sum += v[i];
    const float mu = rsum8(sum) * (1.f/128.f);
    float qs = 0.f;
#pragma unroll
    for (int i = 0; i < 16; ++i) { float d = v[i] - mu; qs += d*d; }
    const float rs = rsqrtf(rsum8(qs) * (1.f/128.f) + LEPS);
#pragma unroll
    for (int i = 0; i < 4; ++i) {
      const int cb = (i*8 + l8) * 4;
      const float4 g  = *(const float4*)(lin_g  + cb);
      const float4 be = *(const float4*)(lin_be + cb);
      const float4 df = *(const float4*)(dense_feats + (long)n*COUT + cb);
      float4 y;
      y.x = lrelu((v[i*4+0]-mu)*rs*g.x + be.x) + df.x;
      y.y = lrelu((v[i*4+1]-mu)*rs*g.y + be.y) + df.y;
      y.z = lrelu((v[i*4+2]-mu)*rs*g.z + be.z) + df.z;
      y.w = lrelu((v[i*4+3]-mu)*rs*g.w + be.w) + df.w;
      *(float4*)(out + (long)n*COUT + cb) = y;
    }
  }
}

// ============================================================================
// Last-resort fallback: fully-fused kernel (used if ws_size is too small)
// ============================================================================
__global__ __launch_bounds__(256)
void pct_fused(
    const float* __restrict__ sparse_xyz,
    const float* __restrict__ sparse_feats,
    const int* __restrict__ nei_inds,
    const float* __restrict__ dense_xyz,
    const float* __restrict__ dense_feats,
    const float* __restrict__ pe_w0, const float* __restrict__ pe_b0,
    const float* __restrict__ pe_g0, const float* __restrict__ pe_be0,
    const float* __restrict__ pe_w1, const float* __restrict__ pe_b1,
    const float* __restrict__ pe_g1, const float* __restrict__ pe_be1,
    const float* __restrict__ wn_w0, const float* __restrict__ wn_b0,
    const float* __restrict__ wn_g0, const float* __restrict__ wn_be0,
    const float* __restrict__ wn_w1, const float* __restrict__ wn_b1,
    const float* __restrict__ wn_g1, const float* __restrict__ wn_be1,
    const float* __restrict__ wn_w2, const float* __restrict__ wn_b2,
    const float* __restrict__ wn_g2, const float* __restrict__ wn_be2,
    const float* __restrict__ lin_w, const float* __restrict__ lin_b,
    const float* __restrict__ lin_g, const float* __restrict__ lin_be,
    float* __restrict__ out)
{
  __shared__ __align__(16) unsigned short feat_s[KNN][CF];
  __shared__ float wts_s[KNN][MM];
  __shared__ float loc_s[KNN][3];
  __shared__ int   nei_s[KNN];
  __shared__ __align__(16) unsigned short out_tile[CF*MM][8];

  const int t  = threadIdx.x;
  const int n0 = blockIdx.x * 8;
  const int k  = t >> 4;
  const int l  = t & 15;

#pragma unroll 1
  for (int p = 0; p < 8; ++p) {
    const int n = n0 + p;
    if (t < KNN) {
      int idx = nei_inds[n*KNN + t];
      nei_s[t] = idx;
      loc_s[t][0] = sparse_xyz[idx*3+0] - dense_xyz[n*3+0];
      loc_s[t][1] = sparse_xyz[idx*3+1] - dense_xyz[n*3+1];
      loc_s[t][2] = sparse_xyz[idx*3+2] - dense_xyz[n*3+2];
    }
    __syncthreads();
    {
      const int gk = t >> 4;
      const int c8 = (t & 15) * 8;
      const float* src = sparse_feats + (long)nei_s[gk]*CIN + c8;
      const float4 va = *(const float4*)(src);
      const float4 vb = *(const float4*)(src + 4);
      unsigned short* dst = &feat_s[gk][c8];
      dst[0] = f2bf(va.x); dst[1] = f2bf(va.y); dst[2] = f2bf(va.z); dst[3] = f2bf(va.w);
      dst[4] = f2bf(vb.x); dst[5] = f2bf(vb.y); dst[6] = f2bf(vb.z); dst[7] = f2bf(vb.w);
    }
    const float x0 = loc_s[k][0], x1 = loc_s[k][1], x2 = loc_s[k][2];
    const int c0 = l, c1 = l + 16;
    float ha = x0*pe_w0[0*PEC+c0] + x1*pe_w0[1*PEC+c0] + x2*pe_w0[2*PEC+c0] + pe_b0[c0];
    float hb = x0*pe_w0[0*PEC+c1] + x1*pe_w0[1*PEC+c1] + x2*pe_w0[2*PEC+c1] + pe_b0[c1];
    {
      float mu = rsum16(ha + hb) * (1.f/32.f);
      float da = ha - mu, db = hb - mu;
      float q  = rsum16(da*da + db*db);
      float rs = rsqrtf(q*(1.f/32.f) + LEPS);
      ha = lrelu(da*rs*pe_g0[c0] + pe_be0[c0]);
      hb = lrelu(db*rs*pe_g0[c1] + pe_be0[c1]);
    }
    float za = pe_b1[c0], zb = pe_b1[c1];
#pragma unroll
    for (int j = 0; j < 16; ++j) {
      float va = __shfl(ha, j, 16);
      float vb = __shfl(hb, j, 16);
      za += va * pe_w1[j*PEC + c0] + vb * pe_w1[(j+16)*PEC + c0];
      zb += va * pe_w1[j*PEC + c1] + vb * pe_w1[(j+16)*PEC + c1];
    }
    {
      float mu = rsum16(za + zb) * (1.f/32.f);
      float da = za - mu, db = zb - mu;
      float q  = rsum16(da*da + db*db);
      float rs = rsqrtf(q*(1.f/32.f) + LEPS);
      feat_s[k][CIN + c0] = f2bf(da*rs*pe_g1[c0] + pe_be1[c0]);
      feat_s[k][CIN + c1] = f2bf(db*rs*pe_g1[c1] + pe_be1[c1]);
    }
    float w0v = x0*wn_w0[0*MM+l] + x1*wn_w0[1*MM+l] + x2*wn_w0[2*MM+l] + wn_b0[l];
    {
      float mu = rsum16(w0v) * (1.f/16.f);
      float d  = w0v - mu;
      float rs = rsqrtf(rsum16(d*d)*(1.f/16.f) + LEPS);
      w0v = lrelu(d*rs*wn_g0[l] + wn_be0[l]);
    }
    float w1v = wn_b1[l];
#pragma unroll
    for (int j = 0; j < 16; ++j)
      w1v += __shfl(w0v, j, 16) * wn_w1[j*MM + l];
    {
      float mu = rsum16(w1v) * (1.f/16.f);
      float d  = w1v - mu;
      float rs = rsqrtf(rsum16(d*d)*(1.f/16.f) + LEPS);
      w1v = lrelu(d*rs*wn_g1[l] + wn_be1[l]);
    }
    float w2v = wn_b2[l];
#pragma unroll
    for (int j = 0; j < 16; ++j)
      w2v += __shfl(w1v, j, 16) * wn_w2[j*MM + l];
    {
      float mu = rsum16(w2v) * (1.f/16.f);
      float d  = w2v - mu;
      float rs = rsqrtf(rsum16(d*d)*(1.f/16.f) + LEPS);
      w2v = d*rs*wn_g2[l] + wn_be2[l];
    }
    wts_s[k][l] = w2v;
    __syncthreads();
    {
      const int m = t & 15;
      const int g = t >> 4;
      float wv[KNN];
#pragma unroll
      for (int kk = 0; kk < KNN; ++kk) wv[kk] = wts_s[kk][m];
#pragma unroll
      for (int j = 0; j < 10; ++j) {
        const int c = g*10 + j;
        float acc = 0.f;
#pragma unroll
        for (int kk = 0; kk < KNN; ++kk)
          acc += bf2f(feat_s[kk][c]) * wv[kk];
        out_tile[c*MM + m][p] = f2bf(acc);
      }
    }
    __syncthreads();
  }
  {
    const int h  = t >> 6;
    const int o0 = (t & 63) * 2;
    float acc0[8], acc1[8];
#pragma unroll
    for (int p = 0; p < 8; ++p) { acc0[p] = 0.f; acc1[p] = 0.f; }
    const int i0 = h * 640;
    for (int i = i0; i < i0 + 640; ++i) {
      const float2 wv = *(const float2*)(lin_w + (long)i*COUT + o0);
      const float wa = wv.x;
      const float wc = wv.y;
      const uint4 r = *(const uint4*)(&out_tile[i][0]);
      const float f0 = bf2f((unsigned short)(r.x & 0xffffu));
      const float f1 = bf2f((unsigned short)(r.x >> 16));
      const float g2 = bf2f((unsigned short)(r.y & 0xffffu));
      const float g3 = bf2f((unsigned short)(r.y >> 16));
      const float g4 = bf2f((unsigned short)(r.z & 0xffffu));
      const float g5 = bf2f((unsigned short)(r.z >> 16));
      const float g6 = bf2f((unsigned short)(r.w & 0xffffu));
      const float g7 = bf2f((unsigned short)(r.w >> 16));
      acc0[0] += f0*wa; acc1[0] += f0*wc;
      acc0[1] += f1*wa; acc1[1] += f1*wc;
      acc0[2] += g2*wa; acc1[2] += g2*wc;
      acc0[3] += g3*wa; acc1[3] += g3*wc;
      acc0[4] += g4*wa; acc1[4] += g4*wc;
      acc0[5] += g5*wa; acc1[5] += g5*wc;
      acc0[6] += g6*wa; acc1[6] += g6*wc;
      acc0[7] += g7*wa; acc1[7] += g7*wc;
    }
    __syncthreads();
    float* red = (float*)&out_tile[0][0];
#pragma unroll
    for (int p = 0; p < 8; ++p) {
      red[((h*8 + p) << 7) + o0    ] = acc0[p];
      red[((h*8 + p) << 7) + o0 + 1] = acc1[p];
    }
    __syncthreads();
    const int p2 = t >> 5, l2 = t & 31;
    const int n  = n0 + p2;
    float v[4];
#pragma unroll
    for (int j = 0; j < 4; ++j) {
      const int o = l2 + (j << 5);
      float sv = red[((0*8 + p2) << 7) + o] + red[((1*8 + p2) << 7) + o]
               + red[((2*8 + p2) << 7) + o] + red[((3*8 + p2) << 7) + o];
      v[j] = sv + lin_b[o];
    }
    float mu = rsum32(v[0] + v[1] + v[2] + v[3]) * (1.f/128.f);
    float q = 0.f;
#pragma unroll
    for (int j = 0; j < 4; ++j) { float d = v[j] - mu; q += d*d; }
    float rs = rsqrtf(rsum32(q) * (1.f/128.f) + LEPS);
#pragma unroll
    for (int j = 0; j < 4; ++j) {
      const int o = l2 + (j << 5);
      float y = (v[j] - mu) * rs * lin_g[o] + lin_be[o];
      y = lrelu(y);
      y += dense_feats[n*COUT + o];
      out[n*COUT + o] = y;
    }
  }
}

extern "C" void kernel_launch(void* const* d_in, const int* in_sizes, int n_in,
                              void* d_out, int out_size, void* d_ws, size_t ws_size,
                              hipStream_t stream) {
  const int Nd = in_sizes[2] / KNN;    // 40000
  const int Ns = in_sizes[1] / CIN;    // 10000
  const size_t a_bytes  = (size_t)Nd * KDIM * 2;       // 204.8 MB
  const size_t w_bytes  = (size_t)KDIM * COUT * 2;     // 655 KB
  const size_t f_bytes  = (size_t)Ns * CIN * 2;        // 2.56 MB
  const bool use_split = (ws_size >= a_bytes + w_bytes + f_bytes)
                         && (Nd % 32 == 0) && ((Ns * CIN) % 4 == 0);

  if (use_split) {
    unsigned short* apack = (unsigned short*)d_ws;
    unsigned short* wpack = (unsigned short*)((char*)d_ws + a_bytes);
    unsigned short* sfb16 = (unsigned short*)((char*)d_ws + a_bytes + w_bytes);

    const int n4 = Ns * CIN / 4;
    pct_prep<<<dim3(160 + (n4 + 255)/256), dim3(256), 0, stream>>>(
      (const float*)d_in[27], wpack, (const float*)d_in[1], sfb16, n4);

    pct_nets<<<dim3(Nd / NPB), dim3(256), 0, stream>>>(
      (const float*)d_in[0],  (const int*)d_in[2],  (const float*)d_in[4],
      (const float*)d_in[7],  (const float*)d_in[8],  (const float*)d_in[9],  (const float*)d_in[10],
      (const float*)d_in[11], (const float*)d_in[12], (const float*)d_in[13], (const float*)d_in[14],
      (const float*)d_in[15], (const float*)d_in[16], (const float*)d_in[17], (const float*)d_in[18],
      (const float*)d_in[19], (const float*)d_in[20], (const float*)d_in[21], (const float*)d_in[22],
      (const float*)d_in[23], (const float*)d_in[24], (const float*)d_in[25], (const float*)d_in[26],
      apack);

    pct_einsum2<<<dim3(Nd / NPB), dim3(256), 0, stream>>>(
      (const int*)d_in[2], sfb16, apack);

    pct_gemm32<<<dim3(Nd / 32), dim3(256), 0, stream>>>(
      apack, wpack,
      (const float*)d_in[28], (const float*)d_in[29], (const float*)d_in[30],
      (const float*)d_in[6], (float*)d_out);
  } else {
    pct_fused<<<dim3(Nd / 8), dim3(256), 0, stream>>>(
      (const float*)d_in[0],  (const float*)d_in[1],  (const int*)d_in[2],
      (const float*)d_in[4],  (const float*)d_in[6],
      (const float*)d_in[7],  (const float*)d_in[8],  (const float*)d_in[9],  (const float*)d_in[10],
      (const float*)d_in[11], (const float*)d_in[12], (const float*)d_in[13], (const float*)d_in[14],
      (const float*)d_in[15], (const float*)d_in[16], (const float*)d_in[17], (const float*)d_in[18],
      (const float*)d_in[19], (const float*)d_in[20], (const float*)d_in[21], (const float*)d_in[22],
      (const float*)d_in[23], (const float*)d_in[24], (const float*)d_in[25], (const float*)d_in[26],
      (const float*)d_in[27], (const float*)d_in[28], (const float*)d_in[29], (const float*)d_in[30],
      (float*)d_out);
  }
}

// Round 7
// 321.264 us; speedup vs baseline: 1.1252x; 1.0211x over previous
//
#include <hip/hip_runtime.h>

#define NPB  16     // dense points per block (einsum kernels)
#define KNN  16     // neighbors
#define CIN  128
#define CF   160    // Cin + PE
#define MM   16     // weightnet out channels
#define PEC  32     // positional encoding channels
#define COUT 128
#define KDIM 2560   // CF * MM
#define LEPS 1e-5f

typedef __bf16 bf16x8 __attribute__((ext_vector_type(8)));
typedef float  f32x4  __attribute__((ext_vector_type(4)));
union U16x8 { uint4 u4; bf16x8 b; unsigned short us[8]; };

// LDS weight-bank offsets (floats)
#define SW_PE_W0   0
#define SW_PE_B0   96
#define SW_PE_G0   128
#define SW_PE_BE0  160
#define SW_PE_W1   192
#define SW_PE_B1   1216
#define SW_PE_G1   1248
#define SW_PE_BE1  1280
#define SW_WN_W0   1312
#define SW_WN_B0   1360
#define SW_WN_G0   1376
#define SW_WN_BE0  1392
#define SW_WN_W1   1408
#define SW_WN_B1   1664
#define SW_WN_G1   1680
#define SW_WN_BE1  1696
#define SW_WN_W2   1712
#define SW_WN_B2   1968
#define SW_WN_G2   1984
#define SW_WN_BE2  2000
#define SW_TOTAL   2016

__device__ __forceinline__ float bf2f(unsigned short b){
  union { unsigned int u; float f; } x; x.u = ((unsigned int)b) << 16; return x.f;
}
__device__ __forceinline__ unsigned short f2bf(float f){
  union { float f; unsigned int u; } x; x.f = f;
  unsigned int r = (x.u + 0x7fffu + ((x.u >> 16) & 1u)) >> 16;
  return (unsigned short)r;
}
// HW RTNE convert via __bf16 cast
__device__ __forceinline__ unsigned short f2b(float f){
  union { __bf16 h; unsigned short u; } v; v.h = (__bf16)f; return v.u;
}
__device__ __forceinline__ float rsum16(float v){
  v += __shfl_xor(v, 8, 16);
  v += __shfl_xor(v, 4, 16);
  v += __shfl_xor(v, 2, 16);
  v += __shfl_xor(v, 1, 16);
  return v;
}
__device__ __forceinline__ float rsum4(float v){
  v += __shfl_xor(v, 2, 4);
  v += __shfl_xor(v, 1, 4);
  return v;
}
__device__ __forceinline__ float rsum32(float v){
  v += __shfl_xor(v, 16, 32);
  v += __shfl_xor(v, 8, 32);
  v += __shfl_xor(v, 4, 32);
  v += __shfl_xor(v, 2, 32);
  v += __shfl_xor(v, 1, 32);
  return v;
}
__device__ __forceinline__ float lrelu(float v){ return v >= 0.f ? v : 0.1f * v; }

template<int N>
__device__ __forceinline__ void ln_inlane(float* v, const float* g, const float* be, bool act){
  float mu = 0.f;
#pragma unroll
  for (int i = 0; i < N; ++i) mu += v[i];
  mu *= (1.f / N);
  float var = 0.f;
#pragma unroll
  for (int i = 0; i < N; ++i) { float d = v[i] - mu; var += d * d; }
  const float rs = rsqrtf(var * (1.f / N) + LEPS);
#pragma unroll
  for (int i = 0; i < N; ++i) {
    float y = (v[i] - mu) * rs * g[i] + be[i];
    v[i] = act ? lrelu(y) : y;
  }
}

// ============================================================================
// Kernel PREP: blocks [0,160) pack lin_w -> wpack fragments; rest convert
// sparse_feats f32 -> bf16 (2.56 MB; fits per-XCD L2 for the gathers).
// ============================================================================
__global__ __launch_bounds__(256)
void pct_prep(const float* __restrict__ lin_w, unsigned short* __restrict__ wpack,
              const float* __restrict__ sf, unsigned short* __restrict__ sfb16,
              const int n4)
{
  const int bid = blockIdx.x;
  if (bid < 160) {
    const int u    = bid * 256 + threadIdx.x;   // 0..40959
    const int lane = u & 63;
    const int tt   = (u >> 6) & 7;
    const int s    = u >> 9;
    const int ipb  = s * 32 + ((lane >> 4) * 8);
    const int nn   = tt * 16 + (lane & 15);
    unsigned short v[8];
#pragma unroll
    for (int j = 0; j < 8; ++j) {
      const int ip  = ipb + j;
      const int r   = ip & 3;
      const int ctl = (ip >> 2) & 1;
      const int qq  = (ip >> 3) & 3;
      const int c16 = (ip >> 5) & 15;
      const int P   = ip >> 9;
      const int c   = P * 32 + ctl * 16 + c16;
      const int m   = qq * 4 + r;
      v[j] = f2bf(lin_w[(long)(c * MM + m) * COUT + nn]);
    }
    *(uint4*)(wpack + (long)u * 8) = *(uint4*)v;
  } else {
    const int i = (bid - 160) * 256 + threadIdx.x;
    if (i >= n4) return;
    const float4 v = ((const float4*)sf)[i];
    union { unsigned short us[4]; uint2 u; } r;
    r.us[0] = f2b(v.x); r.us[1] = f2b(v.y); r.us[2] = f2b(v.z); r.us[3] = f2b(v.w);
    ((uint2*)sfb16)[i] = r.u;
  }
}

// ============================================================================
// Kernel N: per-thread small nets + fragment PACK into apack rows (first 768
// of 2560 ushorts per row; einsum2 consumes before overwriting).
// ============================================================================
__global__ __launch_bounds__(256)
void pct_nets(
    const float* __restrict__ sparse_xyz,
    const int* __restrict__ nei_inds,
    const float* __restrict__ dense_xyz,
    const float* __restrict__ pe_w0, const float* __restrict__ pe_b0,
    const float* __restrict__ pe_g0, const float* __restrict__ pe_be0,
    const float* __restrict__ pe_w1, const float* __restrict__ pe_b1,
    const float* __restrict__ pe_g1, const float* __restrict__ pe_be1,
    const float* __restrict__ wn_w0, const float* __restrict__ wn_b0,
    const float* __restrict__ wn_g0, const float* __restrict__ wn_be0,
    const float* __restrict__ wn_w1, const float* __restrict__ wn_b1,
    const float* __restrict__ wn_g1, const float* __restrict__ wn_be1,
    const float* __restrict__ wn_w2, const float* __restrict__ wn_b2,
    const float* __restrict__ wn_g2, const float* __restrict__ wn_be2,
    unsigned short* __restrict__ apack)
{
  __shared__ float sw[SW_TOTAL];                               // 8064 B
  __shared__ __align__(16) unsigned short wtsf[16 * 256];      // 8 KB A-frags
  __shared__ __align__(16) unsigned short pef[16 * 512];       // 16 KB [p][k][32c]

  const int t     = threadIdx.x;
  const int nbase = blockIdx.x * NPB;

  // ---- stage net weights in LDS ----
  for (int i = t; i < 96;   i += 256) sw[SW_PE_W0 + i] = pe_w0[i];
  for (int i = t; i < 32;   i += 256) {
    sw[SW_PE_B0 + i] = pe_b0[i];  sw[SW_PE_G0 + i] = pe_g0[i];  sw[SW_PE_BE0 + i] = pe_be0[i];
    sw[SW_PE_B1 + i] = pe_b1[i];  sw[SW_PE_G1 + i] = pe_g1[i];  sw[SW_PE_BE1 + i] = pe_be1[i];
  }
  for (int i = t; i < 1024; i += 256) sw[SW_PE_W1 + i] = pe_w1[i];
  for (int i = t; i < 48;   i += 256) sw[SW_WN_W0 + i] = wn_w0[i];
  for (int i = t; i < 16;   i += 256) {
    sw[SW_WN_B0 + i] = wn_b0[i];  sw[SW_WN_G0 + i] = wn_g0[i];  sw[SW_WN_BE0 + i] = wn_be0[i];
    sw[SW_WN_B1 + i] = wn_b1[i];  sw[SW_WN_G1 + i] = wn_g1[i];  sw[SW_WN_BE1 + i] = wn_be1[i];
    sw[SW_WN_B2 + i] = wn_b2[i];  sw[SW_WN_G2 + i] = wn_g2[i];  sw[SW_WN_BE2 + i] = wn_be2[i];
  }
  for (int i = t; i < 256;  i += 256) { sw[SW_WN_W1 + i] = wn_w1[i]; sw[SW_WN_W2 + i] = wn_w2[i]; }
  __syncthreads();

  // ---- nets: thread (p = t>>4, k = t&15) ----
  {
    const int p  = t >> 4;
    const int kk = t & 15;
    const int n  = nbase + p;
    const int idx = nei_inds[n * KNN + kk];
    const float x0 = sparse_xyz[idx*3+0] - dense_xyz[n*3+0];
    const float x1 = sparse_xyz[idx*3+1] - dense_xyz[n*3+1];
    const float x2 = sparse_xyz[idx*3+2] - dense_xyz[n*3+2];

    // pe layer0 (3->32) + LN + act
    float h[32];
#pragma unroll
    for (int c = 0; c < 32; ++c)
      h[c] = x0*sw[SW_PE_W0+c] + x1*sw[SW_PE_W0+32+c] + x2*sw[SW_PE_W0+64+c] + sw[SW_PE_B0+c];
    ln_inlane<32>(h, &sw[SW_PE_G0], &sw[SW_PE_BE0], true);

    // pe layer1 (32->32) + LN (no act)
    float z[32];
#pragma unroll
    for (int c = 0; c < 32; ++c) z[c] = sw[SW_PE_B1 + c];
#pragma unroll 4
    for (int j = 0; j < 32; ++j) {
      const float hj = h[j];
#pragma unroll
      for (int c = 0; c < 32; ++c) z[c] += hj * sw[SW_PE_W1 + j*32 + c];
    }
    ln_inlane<32>(z, &sw[SW_PE_G1], &sw[SW_PE_BE1], false);
    {
      union { unsigned short us[32]; uint4 u4[4]; } zb;
#pragma unroll
      for (int c = 0; c < 32; ++c) zb.us[c] = f2b(z[c]);
      unsigned short* pp_ = pef + p*512 + kk*32;   // [p][k][32c]
#pragma unroll
      for (int j = 0; j < 4; ++j) *(uint4*)(pp_ + j*8) = zb.u4[j];
    }

    // wn layer0 (3->16) + LN + act
    float w[16];
#pragma unroll
    for (int m = 0; m < 16; ++m)
      w[m] = x0*sw[SW_WN_W0+m] + x1*sw[SW_WN_W0+16+m] + x2*sw[SW_WN_W0+32+m] + sw[SW_WN_B0+m];
    ln_inlane<16>(w, &sw[SW_WN_G0], &sw[SW_WN_BE0], true);

    // wn layer1 (16->16) + LN + act
    float z2[16];
#pragma unroll
    for (int m = 0; m < 16; ++m) z2[m] = sw[SW_WN_B1 + m];
#pragma unroll 4
    for (int j = 0; j < 16; ++j) {
      const float wj = w[j];
#pragma unroll
      for (int m = 0; m < 16; ++m) z2[m] += wj * sw[SW_WN_W1 + j*16 + m];
    }
    ln_inlane<16>(z2, &sw[SW_WN_G1], &sw[SW_WN_BE1], true);

    // wn layer2 (16->16) + LN (no act)
#pragma unroll
    for (int m = 0; m < 16; ++m) w[m] = sw[SW_WN_B2 + m];
#pragma unroll 4
    for (int j = 0; j < 16; ++j) {
      const float wj = z2[j];
#pragma unroll
      for (int m = 0; m < 16; ++m) w[m] += wj * sw[SW_WN_W2 + j*16 + m];
    }
    ln_inlane<16>(w, &sw[SW_WN_G2], &sw[SW_WN_BE2], false);
    // A-fragment store: slot lane L=(kk>>3)*16+m holds wts[k=(L>>4)*8+j][m=L&15]
    {
      unsigned short* wf = wtsf + p*256 + ((kk >> 3) << 7) + (kk & 7);
#pragma unroll
      for (int m = 0; m < 16; ++m) wf[m*8] = f2b(w[m]);
    }
  }
  // NO barrier: wave w wrote wtsf/pef for points 4w..4w+3 and packs the same.

  // ---- pack phase: coalesced fragment stores into apack rows ----
  {
    const int lane = t & 63;
    const int wave = t >> 6;
    const int l2   = lane & 31;
    const int ct2  = lane >> 5;        // lanes<32 -> pe ct0 (+af), lanes>=32 -> pe ct1
#pragma unroll
    for (int i = 0; i < 4; ++i) {
      const int p = wave*4 + i;
      unsigned short* fw = apack + (size_t)(nbase + p) * KDIM;
      if (lane < 32) {
        const uint4 a = *(const uint4*)(wtsf + p*256 + lane*8);
        *(uint4*)(fw + lane*8) = a;
      }
      union { unsigned short us[8]; uint4 u4; } o;
#pragma unroll
      for (int j = 0; j < 8; ++j)
        o.us[j] = pef[p*512 + ((l2 >> 4)*8 + j)*32 + ct2*16 + (l2 & 15)];
      *(uint4*)(fw + 256 + ct2*256 + l2*8) = o.u4;
    }
  }
}

// ============================================================================
// Kernel E2: MFMA einsum only (unchanged from round 5).
// ============================================================================
__global__ __launch_bounds__(256, 4)
void pct_einsum2(
    const int* __restrict__ nei_inds,
    const unsigned short* __restrict__ sfb16,
    unsigned short* __restrict__ apack)
{
  __shared__ __align__(16) char stage[4 * 2 * 4096];   // 4 waves x 2 bufs x 4KB

  const int t     = threadIdx.x;
  const int nbase = blockIdx.x * NPB;
  const int lane  = t & 63;
  const int wave  = t >> 6;
  const int q     = lane >> 4;      // k-slice group (0..3); >=2 zero-padded K
  const int mq    = lane & 15;      // c16 column
  char* stw = stage + wave * 8192;

  // neighbor indices for staging (instr t4 of point i uses idx[t4*4 + q])
  int idxall[4][4];
#pragma unroll
  for (int i = 0; i < 4; ++i)
#pragma unroll
    for (int t4 = 0; t4 < 4; ++t4)
      idxall[i][t4] = nei_inds[(nbase + wave*4 + i) * KNN + t4*4 + q];

  U16x8 af[2], pe0[2], pe1[2];
  const uint4 zero4 = {0u, 0u, 0u, 0u};

#define LOADF(i_, b_) do {                                                     \
    const unsigned short* fw_ = apack + (size_t)(nbase + wave*4 + (i_)) * KDIM; \
    af[b_].u4  = (lane < 32) ? *(const uint4*)(fw_ + lane*8) : zero4;          \
    pe0[b_].u4 = *(const uint4*)(fw_ + 256 + (lane & 31)*8);                   \
    pe1[b_].u4 = *(const uint4*)(fw_ + 512 + (lane & 31)*8);                   \
  } while (0)

#define GLDS(i_, b_) do {                                                     \
    _Pragma("unroll")                                                         \
    for (int t4 = 0; t4 < 4; ++t4)                                            \
      __builtin_amdgcn_global_load_lds(                                       \
          (const void*)(sfb16 + (size_t)idxall[i_][t4] * CIN + mq * 8),       \
          (void*)(stw + (b_) * 4096 + t4 * 1024), 16, 0, 0);                  \
  } while (0)

  // prologue: frag + feat tile for point 0
  LOADF(0, 0);
  GLDS(0, 0);

  f32x4 accs[10];
#pragma unroll
  for (int i = 0; i < 4; ++i) {
    const size_t n = (size_t)(nbase + wave*4 + i);

    __builtin_amdgcn_sched_barrier(0);          // fence A_i: pin group boundary
    if (i < 3) { LOADF(i+1, (i+1)&1); GLDS(i+1, (i+1)&1); }
    // vmcnt = #ops younger than this point's {LOADF(3), GLDS(4)}:
    //  i=0: LF1+G1=7 ; i=1: S0(5)+LF2+G2=12 ; i=2: S1(5)+LF3+G3=12 ; i=3: S2=5.
    if (i == 0)      asm volatile("s_waitcnt vmcnt(7)"  ::: "memory");
    else if (i == 3) asm volatile("s_waitcnt vmcnt(5)"  ::: "memory");
    else             asm volatile("s_waitcnt vmcnt(12)" ::: "memory");
    __builtin_amdgcn_sched_barrier(0);          // fence B_i

#pragma unroll
    for (int ct = 0; ct < 10; ++ct) accs[ct] = (f32x4){0.f, 0.f, 0.f, 0.f};

    // B fragments from staged feat tile [16k][128c]; row k = (q&1)*8 + j
    const unsigned short* sb = (const unsigned short*)(stw + (i & 1) * 4096)
                               + (q & 1) * 1024 + mq;
#pragma unroll
    for (int ct = 0; ct < 8; ++ct) {
      U16x8 bf_;
#pragma unroll
      for (int j = 0; j < 8; ++j) bf_.us[j] = sb[j * CIN + ct * 16];
      accs[ct] = __builtin_amdgcn_mfma_f32_16x16x32_bf16(af[i&1].b, bf_.b, accs[ct], 0, 0, 0);
    }
    // pe ctiles straight from registers
    accs[8] = __builtin_amdgcn_mfma_f32_16x16x32_bf16(af[i&1].b, pe0[i&1].b, accs[8], 0, 0, 0);
    accs[9] = __builtin_amdgcn_mfma_f32_16x16x32_bf16(af[i&1].b, pe1[i&1].b, accs[9], 0, 0, 0);

    // store: lane holds D[m=q*4+r][c=ct*16+mq]; i' = P*512+mq*32+q*8+ctl*4+r
    unsigned short* ap = apack + n * KDIM + mq * 32 + q * 8;
#pragma unroll
    for (int P = 0; P < 5; ++P) {
      union { unsigned short us[8]; uint4 u4; } o;
#pragma unroll
      for (int r = 0; r < 4; ++r) {
        o.us[r]     = f2b(accs[2*P    ][r]);
        o.us[4 + r] = f2b(accs[2*P + 1][r]);
      }
      *(uint4*)(ap + P * 512) = o.u4;
    }
  }
#undef LOADF
#undef GLDS
}

// ============================================================================
// Kernel G v6: C[40000x128] = A[40000x2560] @ W. 64 rows/block, 625 blocks,
// 4 waves; wave = ALL 64 rows x 2 col-tiles (M=64, N=32).
// Round-6 post-mortem: v5 (M=16,N=64) made each wave re-read the FULL wpack
// -> 1.6 GB of B L2-reads + A stream thrashing wpack out of L2 -> L2/L3 BW
// bound at 94 us. Wave-tile L2 traffic = Nd*K*2*128*(1/N + 1/M):
// v5 = 1.8 GB, this = 605 MB (A read once block-coop, B 400 MB).
// A staged block-cooperatively (wave stages 16 of 64 rows), double-buffered,
// counted vmcnt(4) + RAW s_barrier (no compiler vmcnt(0) drain) x2/chunk.
// A glds uses aux=2 (NT) so the A stream doesn't evict wpack from L2.
// XOR slot-swizzle as v5 (src pre-swizzled, linear LDS dest).
// ============================================================================
__global__ __launch_bounds__(256)
void pct_gemm64(
    const unsigned short* __restrict__ apack,
    const unsigned short* __restrict__ wpack,
    const float* __restrict__ lin_b, const float* __restrict__ lin_g,
    const float* __restrict__ lin_be, const float* __restrict__ dense_feats,
    float* __restrict__ out)
{
  __shared__ __align__(16) union ShU {
    char  abuf[2][16384];     // [buf][64 rows x 256B], slot-swizzled
    float outs[64][132];      // epilogue tile (aliased; barrier-separated)
  } sh;

  const int t    = threadIdx.x;
  const int lane = t & 63;
  const int wave = t >> 6;          // 0..3 -> col-tiles 2w, 2w+1
  const int n0   = blockIdx.x * 64;
  const int q    = lane >> 4;       // 0..3
  const int mq   = lane & 15;

  const unsigned short* wp0 = wpack + ((size_t)(wave*2) * 64 + lane) * 8;

  f32x4 acc[4][2];
#pragma unroll
  for (int i = 0; i < 4; ++i)
#pragma unroll
    for (int j = 0; j < 2; ++j) acc[i][j] = (f32x4){0.f,0.f,0.f,0.f};

  // Stage chunk c into buffer b: wave stages rows {a*16 + wave*4 + q}.
  // LDS = linear [row][slot]; source slot pre-swizzled (mq ^ (row&7)).
  // aux=2 = NT: A stream marked non-temporal, preserves wpack in L2.
#define STAGE64(c_, b_) do {                                                  \
    _Pragma("unroll")                                                         \
    for (int a_ = 0; a_ < 4; ++a_) {                                          \
      const int r_ = a_*16 + wave*4 + q;                                      \
      const unsigned short* s_ = apack + (size_t)(n0 + r_) * KDIM             \
                               + (c_)*128 + ((mq ^ (r_ & 7)) * 8);            \
      __builtin_amdgcn_global_load_lds((const void*)s_,                       \
          (void*)(sh.abuf[b_] + a_*4096 + wave*1024), 16, 0, 2);              \
    }                                                                         \
  } while (0)

  // One chunk = 4 s-steps; per s-step: 4 A ds_reads (row-tiles) + 2 B loads
  // (col-tiles 2w,2w+1) + 8 MFMA.
#define CHUNK64(c_, b_) do {                                                  \
    _Pragma("unroll")                                                         \
    for (int s_ = 0; s_ < 4; ++s_) {                                          \
      const int sg_ = (c_)*4 + s_;                                            \
      const unsigned short* wpb_ = wp0 + (size_t)sg_ * 4096;                  \
      U16x8 b0_, b1_;                                                         \
      b0_.u4 = *(const uint4*)(wpb_);                                         \
      b1_.u4 = *(const uint4*)(wpb_ + 512);                                   \
      _Pragma("unroll")                                                       \
      for (int i_ = 0; i_ < 4; ++i_) {                                        \
        U16x8 af_;                                                            \
        const char* ar_ = sh.abuf[b_] + (i_*16 + mq)*256                      \
                        + (((s_*4 + q) ^ (mq & 7)) * 16);                     \
        af_.u4 = *(const uint4*)ar_;                                          \
        acc[i_][0] = __builtin_amdgcn_mfma_f32_16x16x32_bf16(af_.b, b0_.b, acc[i_][0], 0,0,0); \
        acc[i_][1] = __builtin_amdgcn_mfma_f32_16x16x32_bf16(af_.b, b1_.b, acc[i_][1], 0,0,0); \
      }                                                                       \
    }                                                                         \
  } while (0)

  STAGE64(0, 0);
#pragma unroll 1
  for (int c = 0; c < 19; ++c) {
    STAGE64(c+1, (c+1) & 1);
    asm volatile("s_waitcnt vmcnt(4)" ::: "memory");   // own STAGE(c) complete
    __builtin_amdgcn_s_barrier();                      // raw: no vmcnt(0) drain
    __builtin_amdgcn_sched_barrier(0);
    CHUNK64(c, c & 1);
    __builtin_amdgcn_s_barrier();                      // readers done before next overwrite
  }
  asm volatile("s_waitcnt vmcnt(0)" ::: "memory");
  __builtin_amdgcn_s_barrier();
  __builtin_amdgcn_sched_barrier(0);
  CHUNK64(19, 1);
#undef STAGE64
#undef CHUNK64

  __syncthreads();   // all reads of abuf done before outs (aliased) writes

  // scatter: acc[i][j][r] = C[row = i*16 + q*4 + r][col = (2*wave+j)*16 + mq]
  {
#pragma unroll
    for (int i = 0; i < 4; ++i)
#pragma unroll
      for (int j = 0; j < 2; ++j)
#pragma unroll
        for (int r = 0; r < 4; ++r)
          sh.outs[i*16 + q*4 + r][(wave*2 + j)*16 + mq] = acc[i][j][r];
  }
  __syncthreads();

  // epilogue: 4 threads/point, 32 cols each (column-interleaved)
  {
    const int p  = t >> 2;
    const int l4 = t & 3;
    const int n  = n0 + p;
    float v[32];
#pragma unroll
    for (int i = 0; i < 8; ++i) {
      const int cb = (i*4 + l4) * 4;
      const float4 r  = *(const float4*)(&sh.outs[p][cb]);
      const float4 bb = *(const float4*)(lin_b + cb);
      v[i*4+0] = r.x + bb.x; v[i*4+1] = r.y + bb.y;
      v[i*4+2] = r.z + bb.z; v[i*4+3] = r.w + bb.w;
    }
    float sum = 0.f;
#pragma unroll
    for (int i = 0; i < 32; ++i) sum += v[i];
    const float mu = rsum4(sum) * (1.f/128.f);
    float qs = 0.f;
#pragma unroll
    for (int i = 0; i < 32; ++i) { float d = v[i] - mu; qs += d*d; }
    const float rs = rsqrtf(rsum4(qs) * (1.f/128.f) + LEPS);
#pragma unroll
    for (int i = 0; i < 8; ++i) {
      const int cb = (i*4 + l4) * 4;
      const float4 g  = *(const float4*)(lin_g  + cb);
      const float4 be = *(const float4*)(lin_be + cb);
      const float4 df = *(const float4*)(dense_feats + (long)n*COUT + cb);
      float4 y;
      y.x = lrelu((v[i*4+0]-mu)*rs*g.x + be.x) + df.x;
      y.y = lrelu((v[i*4+1]-mu)*rs*g.y + be.y) + df.y;
      y.z = lrelu((v[i*4+2]-mu)*rs*g.z + be.z) + df.z;
      y.w = lrelu((v[i*4+3]-mu)*rs*g.w + be.w) + df.w;
      *(float4*)(out + (long)n*COUT + cb) = y;
    }
  }
}

// ============================================================================
// Last-resort fallback: fully-fused kernel (used if ws_size is too small)
// ============================================================================
__global__ __launch_bounds__(256)
void pct_fused(
    const float* __restrict__ sparse_xyz,
    const float* __restrict__ sparse_feats,
    const int* __restrict__ nei_inds,
    const float* __restrict__ dense_xyz,
    const float* __restrict__ dense_feats,
    const float* __restrict__ pe_w0, const float* __restrict__ pe_b0,
    const float* __restrict__ pe_g0, const float* __restrict__ pe_be0,
    const float* __restrict__ pe_w1, const float* __restrict__ pe_b1,
    const float* __restrict__ pe_g1, const float* __restrict__ pe_be1,
    const float* __restrict__ wn_w0, const float* __restrict__ wn_b0,
    const float* __restrict__ wn_g0, const float* __restrict__ wn_be0,
    const float* __restrict__ wn_w1, const float* __restrict__ wn_b1,
    const float* __restrict__ wn_g1, const float* __restrict__ wn_be1,
    const float* __restrict__ wn_w2, const float* __restrict__ wn_b2,
    const float* __restrict__ wn_g2, const float* __restrict__ wn_be2,
    const float* __restrict__ lin_w, const float* __restrict__ lin_b,
    const float* __restrict__ lin_g, const float* __restrict__ lin_be,
    float* __restrict__ out)
{
  __shared__ __align__(16) unsigned short feat_s[KNN][CF];
  __shared__ float wts_s[KNN][MM];
  __shared__ float loc_s[KNN][3];
  __shared__ int   nei_s[KNN];
  __shared__ __align__(16) unsigned short out_tile[CF*MM][8];

  const int t  = threadIdx.x;
  const int n0 = blockIdx.x * 8;
  const int k  = t >> 4;
  const int l  = t & 15;

#pragma unroll 1
  for (int p = 0; p < 8; ++p) {
    const int n = n0 + p;
    if (t < KNN) {
      int idx = nei_inds[n*KNN + t];
      nei_s[t] = idx;
      loc_s[t][0] = sparse_xyz[idx*3+0] - dense_xyz[n*3+0];
      loc_s[t][1] = sparse_xyz[idx*3+1] - dense_xyz[n*3+1];
      loc_s[t][2] = sparse_xyz[idx*3+2] - dense_xyz[n*3+2];
    }
    __syncthreads();
    {
      const int gk = t >> 4;
      const int c8 = (t & 15) * 8;
      const float* src = sparse_feats + (long)nei_s[gk]*CIN + c8;
      const float4 va = *(const float4*)(src);
      const float4 vb = *(const float4*)(src + 4);
      unsigned short* dst = &feat_s[gk][c8];
      dst[0] = f2bf(va.x); dst[1] = f2bf(va.y); dst[2] = f2bf(va.z); dst[3] = f2bf(va.w);
      dst[4] = f2bf(vb.x); dst[5] = f2bf(vb.y); dst[6] = f2bf(vb.z); dst[7] = f2bf(vb.w);
    }
    const float x0 = loc_s[k][0], x1 = loc_s[k][1], x2 = loc_s[k][2];
    const int c0 = l, c1 = l + 16;
    float ha = x0*pe_w0[0*PEC+c0] + x1*pe_w0[1*PEC+c0] + x2*pe_w0[2*PEC+c0] + pe_b0[c0];
    float hb = x0*pe_w0[0*PEC+c1] + x1*pe_w0[1*PEC+c1] + x2*pe_w0[2*PEC+c1] + pe_b0[c1];
    {
      float mu = rsum16(ha + hb) * (1.f/32.f);
      float da = ha - mu, db = hb - mu;
      float q  = rsum16(da*da + db*db);
      float rs = rsqrtf(q*(1.f/32.f) + LEPS);
      ha = lrelu(da*rs*pe_g0[c0] + pe_be0[c0]);
      hb = lrelu(db*rs*pe_g0[c1] + pe_be0[c1]);
    }
    float za = pe_b1[c0], zb = pe_b1[c1];
#pragma unroll
    for (int j = 0; j < 16; ++j) {
      float va = __shfl(ha, j, 16);
      float vb = __shfl(hb, j, 16);
      za += va * pe_w1[j*PEC + c0] + vb * pe_w1[(j+16)*PEC + c0];
      zb += va * pe_w1[j*PEC + c1] + vb * pe_w1[(j+16)*PEC + c1];
    }
    {
      float mu = rsum16(za + zb) * (1.f/32.f);
      float da = za - mu, db = zb - mu;
      float q  = rsum16(da*da + db*db);
      float rs = rsqrtf(q*(1.f/32.f) + LEPS);
      feat_s[k][CIN + c0] = f2bf(da*rs*pe_g1[c0] + pe_be1[c0]);
      feat_s[k][CIN + c1] = f2bf(db*rs*pe_g1[c1] + pe_be1[c1]);
    }
    float w0v = x0*wn_w0[0*MM+l] + x1*wn_w0[1*MM+l] + x2*wn_w0[2*MM+l] + wn_b0[l];
    {
      float mu = rsum16(w0v) * (1.f/16.f);
      float d  = w0v - mu;
      float rs = rsqrtf(rsum16(d*d)*(1.f/16.f) + LEPS);
      w0v = lrelu(d*rs*wn_g0[l] + wn_be0[l]);
    }
    float w1v = wn_b1[l];
#pragma unroll
    for (int j = 0; j < 16; ++j)
      w1v += __shfl(w0v, j, 16) * wn_w1[j*MM + l];
    {
      float mu = rsum16(w1v) * (1.f/16.f);
      float d  = w1v - mu;
      float rs = rsqrtf(rsum16(d*d)*(1.f/16.f) + LEPS);
      w1v = lrelu(d*rs*wn_g1[l] + wn_be1[l]);
    }
    float w2v = wn_b2[l];
#pragma unroll
    for (int j = 0; j < 16; ++j)
      w2v += __shfl(w1v, j, 16) * wn_w2[j*MM + l];
    {
      float mu = rsum16(w2v) * (1.f/16.f);
      float d  = w2v - mu;
      float rs = rsqrtf(rsum16(d*d)*(1.f/16.f) + LEPS);
      w2v = d*rs*wn_g2[l] + wn_be2[l];
    }
    wts_s[k][l] = w2v;
    __syncthreads();
    {
      const int m = t & 15;
      const int g = t >> 4;
      float wv[KNN];
#pragma unroll
      for (int kk = 0; kk < KNN; ++kk) wv[kk] = wts_s[kk][m];
#pragma unroll
      for (int j = 0; j < 10; ++j) {
        const int c = g*10 + j;
        float acc = 0.f;
#pragma unroll
        for (int kk = 0; kk < KNN; ++kk)
          acc += bf2f(feat_s[kk][c]) * wv[kk];
        out_tile[c*MM + m][p] = f2bf(acc);
      }
    }
    __syncthreads();
  }
  {
    const int h  = t >> 6;
    const int o0 = (t & 63) * 2;
    float acc0[8], acc1[8];
#pragma unroll
    for (int p = 0; p < 8; ++p) { acc0[p] = 0.f; acc1[p] = 0.f; }
    const int i0 = h * 640;
    for (int i = i0; i < i0 + 640; ++i) {
      const float2 wv = *(const float2*)(lin_w + (long)i*COUT + o0);
      const float wa = wv.x;
      const float wc = wv.y;
      const uint4 r = *(const uint4*)(&out_tile[i][0]);
      const float f0 = bf2f((unsigned short)(r.x & 0xffffu));
      const float f1 = bf2f((unsigned short)(r.x >> 16));
      const float g2 = bf2f((unsigned short)(r.y & 0xffffu));
      const float g3 = bf2f((unsigned short)(r.y >> 16));
      const float g4 = bf2f((unsigned short)(r.z & 0xffffu));
      const float g5 = bf2f((unsigned short)(r.z >> 16));
      const float g6 = bf2f((unsigned short)(r.w & 0xffffu));
      const float g7 = bf2f((unsigned short)(r.w >> 16));
      acc0[0] += f0*wa; acc1[0] += f0*wc;
      acc0[1] += f1*wa; acc1[1] += f1*wc;
      acc0[2] += g2*wa; acc1[2] += g2*wc;
      acc0[3] += g3*wa; acc1[3] += g3*wc;
      acc0[4] += g4*wa; acc1[4] += g4*wc;
      acc0[5] += g5*wa; acc1[5] += g5*wc;
      acc0[6] += g6*wa; acc1[6] += g6*wc;
      acc0[7] += g7*wa; acc1[7] += g7*wc;
    }
    __syncthreads();
    float* red = (float*)&out_tile[0][0];
#pragma unroll
    for (int p = 0; p < 8; ++p) {
      red[((h*8 + p) << 7) + o0    ] = acc0[p];
      red[((h*8 + p) << 7) + o0 + 1] = acc1[p];
    }
    __syncthreads();
    const int p2 = t >> 5, l2 = t & 31;
    const int n  = n0 + p2;
    float v[4];
#pragma unroll
    for (int j = 0; j < 4; ++j) {
      const int o = l2 + (j << 5);
      float sv = red[((0*8 + p2) << 7) + o] + red[((1*8 + p2) << 7) + o]
               + red[((2*8 + p2) << 7) + o] + red[((3*8 + p2) << 7) + o];
      v[j] = sv + lin_b[o];
    }
    float mu = rsum32(v[0] + v[1] + v[2] + v[3]) * (1.f/128.f);
    float q = 0.f;
#pragma unroll
    for (int j = 0; j < 4; ++j) { float d = v[j] - mu; q += d*d; }
    float rs = rsqrtf(rsum32(q) * (1.f/128.f) + LEPS);
#pragma unroll
    for (int j = 0; j < 4; ++j) {
      const int o = l2 + (j << 5);
      float y = (v[j] - mu) * rs * lin_g[o] + lin_be[o];
      y = lrelu(y);
      y += dense_feats[n*COUT + o];
      out[n*COUT + o] = y;
    }
  }
}

extern "C" void kernel_launch(void* const* d_in, const int* in_sizes, int n_in,
                              void* d_out, int out_size, void* d_ws, size_t ws_size,
                              hipStream_t stream) {
  const int Nd = in_sizes[2] / KNN;    // 40000
  const int Ns = in_sizes[1] / CIN;    // 10000
  const size_t a_bytes  = (size_t)Nd * KDIM * 2;       // 204.8 MB
  const size_t w_bytes  = (size_t)KDIM * COUT * 2;     // 655 KB
  const size_t f_bytes  = (size_t)Ns * CIN * 2;        // 2.56 MB
  const bool use_split = (ws_size >= a_bytes + w_bytes + f_bytes)
                         && (Nd % 64 == 0) && ((Ns * CIN) % 4 == 0);

  if (use_split) {
    unsigned short* apack = (unsigned short*)d_ws;
    unsigned short* wpack = (unsigned short*)((char*)d_ws + a_bytes);
    unsigned short* sfb16 = (unsigned short*)((char*)d_ws + a_bytes + w_bytes);

    const int n4 = Ns * CIN / 4;
    pct_prep<<<dim3(160 + (n4 + 255)/256), dim3(256), 0, stream>>>(
      (const float*)d_in[27], wpack, (const float*)d_in[1], sfb16, n4);

    pct_nets<<<dim3(Nd / NPB), dim3(256), 0, stream>>>(
      (const float*)d_in[0],  (const int*)d_in[2],  (const float*)d_in[4],
      (const float*)d_in[7],  (const float*)d_in[8],  (const float*)d_in[9],  (const float*)d_in[10],
      (const float*)d_in[11], (const float*)d_in[12], (const float*)d_in[13], (const float*)d_in[14],
      (const float*)d_in[15], (const float*)d_in[16], (const float*)d_in[17], (const float*)d_in[18],
      (const float*)d_in[19], (const float*)d_in[20], (const float*)d_in[21], (const float*)d_in[22],
      (const float*)d_in[23], (const float*)d_in[24], (const float*)d_in[25], (const float*)d_in[26],
      apack);

    pct_einsum2<<<dim3(Nd / NPB), dim3(256), 0, stream>>>(
      (const int*)d_in[2], sfb16, apack);

    pct_gemm64<<<dim3(Nd / 64), dim3(256), 0, stream>>>(
      apack, wpack,
      (const float*)d_in[28], (const float*)d_in[29], (const float*)d_in[30],
      (const float*)d_in[6], (float*)d_out);
  } else {
    pct_fused<<<dim3(Nd / 8), dim3(256), 0, stream>>>(
      (const float*)d_in[0],  (const float*)d_in[1],  (const int*)d_in[2],
      (const float*)d_in[4],  (const float*)d_in[6],
      (const float*)d_in[7],  (const float*)d_in[8],  (const float*)d_in[9],  (const float*)d_in[10],
      (const float*)d_in[11], (const float*)d_in[12], (const float*)d_in[13], (const float*)d_in[14],
      (const float*)d_in[15], (const float*)d_in[16], (const float*)d_in[17], (const float*)d_in[18],
      (const float*)d_in[19], (const float*)d_in[20], (const float*)d_in[21], (const float*)d_in[22],
      (const float*)d_in[23], (const float*)d_in[24], (const float*)d_in[25], (const float*)d_in[26],
      (const float*)d_in[27], (const float*)d_in[28], (const float*)d_in[29], (const float*)d_in[30],
      (float*)d_out);
  }
}

// Round 8
// 284.139 us; speedup vs baseline: 1.2722x; 1.1307x over previous
//
#include <hip/hip_runtime.h>

#define NPB  16     // dense points per block
#define KNN  16     // neighbors
#define CIN  128
#define CF   160    // Cin + PE
#define MM   16     // weightnet out channels
#define PEC  32     // positional encoding channels
#define COUT 128
#define KDIM 2560   // CF * MM
#define FRE  768    // fragw elems per point: af(256) + pe0(256) + pe1(256)
#define LEPS 1e-5f

typedef __bf16 bf16x8 __attribute__((ext_vector_type(8)));
typedef float  f32x4  __attribute__((ext_vector_type(4)));
union U16x8 { uint4 u4; bf16x8 b; unsigned short us[8]; };

// LDS weight-bank offsets (floats)
#define SW_PE_W0   0
#define SW_PE_B0   96
#define SW_PE_G0   128
#define SW_PE_BE0  160
#define SW_PE_W1   192
#define SW_PE_B1   1216
#define SW_PE_G1   1248
#define SW_PE_BE1  1280
#define SW_WN_W0   1312
#define SW_WN_B0   1360
#define SW_WN_G0   1376
#define SW_WN_BE0  1392
#define SW_WN_W1   1408
#define SW_WN_B1   1664
#define SW_WN_G1   1680
#define SW_WN_BE1  1696
#define SW_WN_W2   1712
#define SW_WN_B2   1968
#define SW_WN_G2   1984
#define SW_WN_BE2  2000
#define SW_TOTAL   2016

__device__ __forceinline__ float bf2f(unsigned short b){
  union { unsigned int u; float f; } x; x.u = ((unsigned int)b) << 16; return x.f;
}
__device__ __forceinline__ unsigned short f2bf(float f){
  union { float f; unsigned int u; } x; x.f = f;
  unsigned int r = (x.u + 0x7fffu + ((x.u >> 16) & 1u)) >> 16;
  return (unsigned short)r;
}
// HW RTNE convert via __bf16 cast
__device__ __forceinline__ unsigned short f2b(float f){
  union { __bf16 h; unsigned short u; } v; v.h = (__bf16)f; return v.u;
}
__device__ __forceinline__ float rsum16(float v){
  v += __shfl_xor(v, 8, 16);
  v += __shfl_xor(v, 4, 16);
  v += __shfl_xor(v, 2, 16);
  v += __shfl_xor(v, 1, 16);
  return v;
}
__device__ __forceinline__ float rsum32(float v){
  v += __shfl_xor(v, 16, 32);
  v += __shfl_xor(v, 8, 32);
  v += __shfl_xor(v, 4, 32);
  v += __shfl_xor(v, 2, 32);
  v += __shfl_xor(v, 1, 32);
  return v;
}
__device__ __forceinline__ float lrelu(float v){ return v >= 0.f ? v : 0.1f * v; }

template<int N>
__device__ __forceinline__ void ln_inlane(float* v, const float* g, const float* be, bool act){
  float mu = 0.f;
#pragma unroll
  for (int i = 0; i < N; ++i) mu += v[i];
  mu *= (1.f / N);
  float var = 0.f;
#pragma unroll
  for (int i = 0; i < N; ++i) { float d = v[i] - mu; var += d * d; }
  const float rs = rsqrtf(var * (1.f / N) + LEPS);
#pragma unroll
  for (int i = 0; i < N; ++i) {
    float y = (v[i] - mu) * rs * g[i] + be[i];
    v[i] = act ? lrelu(y) : y;
  }
}

// ============================================================================
// Kernel PREP: blocks [0,160) pack lin_w -> wpack fragments; rest convert
// sparse_feats f32 -> bf16 (2.56 MB; fits per-XCD L2 for the gathers).
// wpack fragment (s,tt,lane,j): i' = s*32+(lane>>4)*8+j, n = tt*16+(lane&15),
// at wpack[((s*8+tt)*64+lane)*8 + j], where
// i' = P*512 + c16*32 + q*8 + ctl*4 + r, c = P*32+ctl*16+c16, m = q*4+r,
// lin_w row = c*16 + m.  (Same contract the einsum's D emitter uses.)
// ============================================================================
__global__ __launch_bounds__(256)
void pct_prep(const float* __restrict__ lin_w, unsigned short* __restrict__ wpack,
              const float* __restrict__ sf, unsigned short* __restrict__ sfb16,
              const int n4)
{
  const int bid = blockIdx.x;
  if (bid < 160) {
    const int u    = bid * 256 + threadIdx.x;   // 0..40959
    const int lane = u & 63;
    const int tt   = (u >> 6) & 7;
    const int s    = u >> 9;
    const int ipb  = s * 32 + ((lane >> 4) * 8);
    const int nn   = tt * 16 + (lane & 15);
    unsigned short v[8];
#pragma unroll
    for (int j = 0; j < 8; ++j) {
      const int ip  = ipb + j;
      const int r   = ip & 3;
      const int ctl = (ip >> 2) & 1;
      const int qq  = (ip >> 3) & 3;
      const int c16 = (ip >> 5) & 15;
      const int P   = ip >> 9;
      const int c   = P * 32 + ctl * 16 + c16;
      const int m   = qq * 4 + r;
      v[j] = f2bf(lin_w[(long)(c * MM + m) * COUT + nn]);
    }
    *(uint4*)(wpack + (long)u * 8) = *(uint4*)v;
  } else {
    const int i = (bid - 160) * 256 + threadIdx.x;
    if (i >= n4) return;
    const float4 v = ((const float4*)sf)[i];
    union { unsigned short us[4]; uint2 u; } r;
    r.us[0] = f2b(v.x); r.us[1] = f2b(v.y); r.us[2] = f2b(v.z); r.us[3] = f2b(v.w);
    ((uint2*)sfb16)[i] = r.u;
  }
}

// ============================================================================
// Kernel N: per-thread small nets + fragment PACK to fragw (61.4 MB).
// Per-point frag layout (ushort offsets within FRE=768):
//   [0..256)   af  : A-frag, lanes<32, 8 ea  (wts[k=(L>>4)*8+j][m=L&15])
//   [256..512) pe0 : B-frag ct0, [l2<32][8]
//   [512..768) pe1 : B-frag ct1, [l2<32][8]
// ============================================================================
__global__ __launch_bounds__(256)
void pct_nets(
    const float* __restrict__ sparse_xyz,
    const int* __restrict__ nei_inds,
    const float* __restrict__ dense_xyz,
    const float* __restrict__ pe_w0, const float* __restrict__ pe_b0,
    const float* __restrict__ pe_g0, const float* __restrict__ pe_be0,
    const float* __restrict__ pe_w1, const float* __restrict__ pe_b1,
    const float* __restrict__ pe_g1, const float* __restrict__ pe_be1,
    const float* __restrict__ wn_w0, const float* __restrict__ wn_b0,
    const float* __restrict__ wn_g0, const float* __restrict__ wn_be0,
    const float* __restrict__ wn_w1, const float* __restrict__ wn_b1,
    const float* __restrict__ wn_g1, const float* __restrict__ wn_be1,
    const float* __restrict__ wn_w2, const float* __restrict__ wn_b2,
    const float* __restrict__ wn_g2, const float* __restrict__ wn_be2,
    unsigned short* __restrict__ fragw)
{
  __shared__ float sw[SW_TOTAL];                               // 8064 B
  __shared__ __align__(16) unsigned short wtsf[16 * 256];      // 8 KB A-frags
  __shared__ __align__(16) unsigned short pef[16 * 512];       // 16 KB [p][k][32c]

  const int t     = threadIdx.x;
  const int nbase = blockIdx.x * NPB;

  // ---- stage net weights in LDS ----
  for (int i = t; i < 96;   i += 256) sw[SW_PE_W0 + i] = pe_w0[i];
  for (int i = t; i < 32;   i += 256) {
    sw[SW_PE_B0 + i] = pe_b0[i];  sw[SW_PE_G0 + i] = pe_g0[i];  sw[SW_PE_BE0 + i] = pe_be0[i];
    sw[SW_PE_B1 + i] = pe_b1[i];  sw[SW_PE_G1 + i] = pe_g1[i];  sw[SW_PE_BE1 + i] = pe_be1[i];
  }
  for (int i = t; i < 1024; i += 256) sw[SW_PE_W1 + i] = pe_w1[i];
  for (int i = t; i < 48;   i += 256) sw[SW_WN_W0 + i] = wn_w0[i];
  for (int i = t; i < 16;   i += 256) {
    sw[SW_WN_B0 + i] = wn_b0[i];  sw[SW_WN_G0 + i] = wn_g0[i];  sw[SW_WN_BE0 + i] = wn_be0[i];
    sw[SW_WN_B1 + i] = wn_b1[i];  sw[SW_WN_G1 + i] = wn_g1[i];  sw[SW_WN_BE1 + i] = wn_be1[i];
    sw[SW_WN_B2 + i] = wn_b2[i];  sw[SW_WN_G2 + i] = wn_g2[i];  sw[SW_WN_BE2 + i] = wn_be2[i];
  }
  for (int i = t; i < 256;  i += 256) { sw[SW_WN_W1 + i] = wn_w1[i]; sw[SW_WN_W2 + i] = wn_w2[i]; }
  __syncthreads();

  // ---- nets: thread (p = t>>4, k = t&15) ----
  {
    const int p  = t >> 4;
    const int kk = t & 15;
    const int n  = nbase + p;
    const int idx = nei_inds[n * KNN + kk];
    const float x0 = sparse_xyz[idx*3+0] - dense_xyz[n*3+0];
    const float x1 = sparse_xyz[idx*3+1] - dense_xyz[n*3+1];
    const float x2 = sparse_xyz[idx*3+2] - dense_xyz[n*3+2];

    // pe layer0 (3->32) + LN + act
    float h[32];
#pragma unroll
    for (int c = 0; c < 32; ++c)
      h[c] = x0*sw[SW_PE_W0+c] + x1*sw[SW_PE_W0+32+c] + x2*sw[SW_PE_W0+64+c] + sw[SW_PE_B0+c];
    ln_inlane<32>(h, &sw[SW_PE_G0], &sw[SW_PE_BE0], true);

    // pe layer1 (32->32) + LN (no act)
    float z[32];
#pragma unroll
    for (int c = 0; c < 32; ++c) z[c] = sw[SW_PE_B1 + c];
#pragma unroll 4
    for (int j = 0; j < 32; ++j) {
      const float hj = h[j];
#pragma unroll
      for (int c = 0; c < 32; ++c) z[c] += hj * sw[SW_PE_W1 + j*32 + c];
    }
    ln_inlane<32>(z, &sw[SW_PE_G1], &sw[SW_PE_BE1], false);
    {
      union { unsigned short us[32]; uint4 u4[4]; } zb;
#pragma unroll
      for (int c = 0; c < 32; ++c) zb.us[c] = f2b(z[c]);
      unsigned short* pp_ = pef + p*512 + kk*32;   // [p][k][32c]
#pragma unroll
      for (int j = 0; j < 4; ++j) *(uint4*)(pp_ + j*8) = zb.u4[j];
    }

    // wn layer0 (3->16) + LN + act
    float w[16];
#pragma unroll
    for (int m = 0; m < 16; ++m)
      w[m] = x0*sw[SW_WN_W0+m] + x1*sw[SW_WN_W0+16+m] + x2*sw[SW_WN_W0+32+m] + sw[SW_WN_B0+m];
    ln_inlane<16>(w, &sw[SW_WN_G0], &sw[SW_WN_BE0], true);

    // wn layer1 (16->16) + LN + act
    float z2[16];
#pragma unroll
    for (int m = 0; m < 16; ++m) z2[m] = sw[SW_WN_B1 + m];
#pragma unroll 4
    for (int j = 0; j < 16; ++j) {
      const float wj = w[j];
#pragma unroll
      for (int m = 0; m < 16; ++m) z2[m] += wj * sw[SW_WN_W1 + j*16 + m];
    }
    ln_inlane<16>(z2, &sw[SW_WN_G1], &sw[SW_WN_BE1], true);

    // wn layer2 (16->16) + LN (no act)
#pragma unroll
    for (int m = 0; m < 16; ++m) w[m] = sw[SW_WN_B2 + m];
#pragma unroll 4
    for (int j = 0; j < 16; ++j) {
      const float wj = z2[j];
#pragma unroll
      for (int m = 0; m < 16; ++m) w[m] += wj * sw[SW_WN_W2 + j*16 + m];
    }
    ln_inlane<16>(w, &sw[SW_WN_G2], &sw[SW_WN_BE2], false);
    // A-fragment store: slot lane L=(kk>>3)*16+m holds wts[k=(L>>4)*8+j][m=L&15]
    {
      unsigned short* wf = wtsf + p*256 + ((kk >> 3) << 7) + (kk & 7);
#pragma unroll
      for (int m = 0; m < 16; ++m) wf[m*8] = f2b(w[m]);
    }
  }
  // NO barrier: wave w wrote wtsf/pef for points 4w..4w+3 and packs the same.

  // ---- pack phase: coalesced fragment stores into fragw ----
  {
    const int lane = t & 63;
    const int wave = t >> 6;
    const int l2   = lane & 31;
    const int ct2  = lane >> 5;        // lanes<32 -> pe ct0 (+af), lanes>=32 -> pe ct1
#pragma unroll
    for (int i = 0; i < 4; ++i) {
      const int p = wave*4 + i;
      unsigned short* fw = fragw + (size_t)(nbase + p) * FRE;
      if (lane < 32) {
        const uint4 a = *(const uint4*)(wtsf + p*256 + lane*8);
        *(uint4*)(fw + lane*8) = a;
      }
      union { unsigned short us[8]; uint4 u4; } o;
#pragma unroll
      for (int j = 0; j < 8; ++j)
        o.us[j] = pef[p*512 + ((l2 >> 4)*8 + j)*32 + ct2*16 + (l2 & 15)];
      *(uint4*)(fw + 256 + ct2*256 + l2*8) = o.u4;
    }
  }
}

// ============================================================================
// Kernel EG (fused einsum + final GEMM): eliminates the 205 MB apack
// round-trip and the separate gemm kernel.
// Block = 16 points, 4 waves. Wave w: einsum for points 4w..4w+3;
// gemm col-tiles 2w, 2w+1.
// Per K-chunk P (i' in [P*512, P*512+512)):
//   einsum: 2 MFMA/point -> D chunk -> bf16 ds_write to aL[p] (XOR-swizzled,
//           exact apack i' layout: elem off = mq*32+q*8+ctl*4+r)
//   barrier; gemm partial: 16 k-tiles vs wpack (same i' contract); barrier.
// aL swizzle: byte_off ^= (row&7)<<4 on BOTH write and read (writer = dense
// 1KB/wave store, conflict-free; reader 2-way = free).
// LDS: feats 64KB + aL 16KB = 80KB -> 2 blocks/CU; outs aliased over feats.
// ============================================================================
__global__ __launch_bounds__(256)
void pct_eg(
    const int* __restrict__ nei_inds,
    const unsigned short* __restrict__ sfb16,
    const unsigned short* __restrict__ fragw,
    const unsigned short* __restrict__ wpack,
    const float* __restrict__ lin_b, const float* __restrict__ lin_g,
    const float* __restrict__ lin_be, const float* __restrict__ dense_feats,
    float* __restrict__ out)
{
  __shared__ __align__(16) union FU {
    unsigned short feats[16][2048];   // [p][16k][128c] bf16, 64 KB
    float outs[16][132];              // epilogue tile (aliased; barriered)
  } fu;
  __shared__ __align__(16) unsigned short aL[16][512];   // 16 KB bridge

  const int t     = threadIdx.x;
  const int nbase = blockIdx.x * NPB;
  const int lane  = t & 63;
  const int wave  = t >> 6;
  const int q     = lane >> 4;      // 0..3
  const int mq    = lane & 15;

  // neighbor indices (stage instr t4 of point i uses idx[t4*4 + q])
  int idxall[4][4];
#pragma unroll
  for (int i = 0; i < 4; ++i)
#pragma unroll
    for (int t4 = 0; t4 < 4; ++t4)
      idxall[i][t4] = nei_inds[(nbase + wave*4 + i) * KNN + t4*4 + q];

  // ---- stage: feat tiles for own 4 points (16 glds) + frags (12 loads) ----
  U16x8 af[4], pe0[4], pe1[4];
  const uint4 zero4 = {0u, 0u, 0u, 0u};
#pragma unroll
  for (int i = 0; i < 4; ++i) {
    const int p = wave*4 + i;
#pragma unroll
    for (int t4 = 0; t4 < 4; ++t4)
      __builtin_amdgcn_global_load_lds(
          (const void*)(sfb16 + (size_t)idxall[i][t4] * CIN + mq * 8),
          (void*)((char*)fu.feats[p] + t4 * 1024), 16, 0, 0);
    const unsigned short* fw = fragw + (size_t)(nbase + p) * FRE;
    af[i].u4  = (lane < 32) ? *(const uint4*)(fw + lane*8) : zero4;
    pe0[i].u4 = *(const uint4*)(fw + 256 + (lane & 31)*8);
    pe1[i].u4 = *(const uint4*)(fw + 512 + (lane & 31)*8);
  }
  __syncthreads();   // all feats + frags resident

  f32x4 acc0 = {0.f,0.f,0.f,0.f}, acc1 = {0.f,0.f,0.f,0.f};
  const unsigned short* wpl = wpack + ((size_t)(wave*2) * 64 + lane) * 8;

#pragma unroll 1
  for (int P = 0; P < 5; ++P) {
    // ---- einsum phase: D chunk for own 4 points -> aL ----
#pragma unroll
    for (int i = 0; i < 4; ++i) {
      const int p = wave*4 + i;
      f32x4 a0 = {0.f,0.f,0.f,0.f}, a1 = {0.f,0.f,0.f,0.f};
      if (P < 4) {
        const unsigned short* sb = &fu.feats[p][0] + (q & 1) * 1024 + mq;
        U16x8 b0_, b1_;
#pragma unroll
        for (int j = 0; j < 8; ++j) b0_.us[j] = sb[j * CIN + (2*P    ) * 16];
#pragma unroll
        for (int j = 0; j < 8; ++j) b1_.us[j] = sb[j * CIN + (2*P + 1) * 16];
        a0 = __builtin_amdgcn_mfma_f32_16x16x32_bf16(af[i].b, b0_.b, a0, 0, 0, 0);
        a1 = __builtin_amdgcn_mfma_f32_16x16x32_bf16(af[i].b, b1_.b, a1, 0, 0, 0);
      } else {
        a0 = __builtin_amdgcn_mfma_f32_16x16x32_bf16(af[i].b, pe0[i].b, a0, 0, 0, 0);
        a1 = __builtin_amdgcn_mfma_f32_16x16x32_bf16(af[i].b, pe1[i].b, a1, 0, 0, 0);
      }
      // D write: lane holds D[m=q*4+r][c-slice]; chunk elem off = mq*32+q*8+ctl*4+r
      union { unsigned short us[8]; uint4 u4; } o;
#pragma unroll
      for (int r = 0; r < 4; ++r) { o.us[r] = f2b(a0[r]); o.us[4+r] = f2b(a1[r]); }
      *(uint4*)((char*)aL[p] + ((mq*64 + q*16) ^ ((p & 7) << 4))) = o.u4;
    }
    __syncthreads();   // aL chunk complete (orders ds_writes)

    // ---- gemm phase: 16 k-tiles of this chunk ----
#pragma unroll
    for (int s = 0; s < 16; ++s) {
      const int sg = P*16 + s;
      U16x8 af2;
      af2.u4 = *(const uint4*)((char*)aL[mq] + ((s*64 + q*16) ^ ((mq & 7) << 4)));
      const unsigned short* wpb = wpl + (size_t)sg * 4096;
      U16x8 b0_, b1_;
      b0_.u4 = *(const uint4*)(wpb);
      b1_.u4 = *(const uint4*)(wpb + 512);
      acc0 = __builtin_amdgcn_mfma_f32_16x16x32_bf16(af2.b, b0_.b, acc0, 0, 0, 0);
      acc1 = __builtin_amdgcn_mfma_f32_16x16x32_bf16(af2.b, b1_.b, acc1, 0, 0, 0);
    }
    __syncthreads();   // done reading aL before next chunk overwrites
  }

  // ---- scatter: C[row=q*4+r][col=(2w+j)*16+mq], rows = block points ----
  // (feats dead since P=3; outs aliases it; barriers above separate uses)
#pragma unroll
  for (int r = 0; r < 4; ++r) {
    fu.outs[q*4 + r][(wave*2    )*16 + mq] = acc0[r];
    fu.outs[q*4 + r][(wave*2 + 1)*16 + mq] = acc1[r];
  }
  __syncthreads();

  // ---- epilogue: 16 threads/point, 8 cols each ----
  {
    const int p   = t >> 4;
    const int l16 = t & 15;
    const int n   = nbase + p;
    float v[8];
#pragma unroll
    for (int i = 0; i < 2; ++i) {
      const int cb = (i*16 + l16) * 4;
      const float4 r  = *(const float4*)(&fu.outs[p][cb]);
      const float4 bb = *(const float4*)(lin_b + cb);
      v[i*4+0] = r.x + bb.x; v[i*4+1] = r.y + bb.y;
      v[i*4+2] = r.z + bb.z; v[i*4+3] = r.w + bb.w;
    }
    float sum = 0.f;
#pragma unroll
    for (int i = 0; i < 8; ++i) sum += v[i];
    const float mu = rsum16(sum) * (1.f/128.f);
    float qs = 0.f;
#pragma unroll
    for (int i = 0; i < 8; ++i) { float d = v[i] - mu; qs += d*d; }
    const float rs = rsqrtf(rsum16(qs) * (1.f/128.f) + LEPS);
#pragma unroll
    for (int i = 0; i < 2; ++i) {
      const int cb = (i*16 + l16) * 4;
      const float4 g  = *(const float4*)(lin_g  + cb);
      const float4 be = *(const float4*)(lin_be + cb);
      const float4 df = *(const float4*)(dense_feats + (long)n*COUT + cb);
      float4 y;
      y.x = lrelu((v[i*4+0]-mu)*rs*g.x + be.x) + df.x;
      y.y = lrelu((v[i*4+1]-mu)*rs*g.y + be.y) + df.y;
      y.z = lrelu((v[i*4+2]-mu)*rs*g.z + be.z) + df.z;
      y.w = lrelu((v[i*4+3]-mu)*rs*g.w + be.w) + df.w;
      *(float4*)(out + (long)n*COUT + cb) = y;
    }
  }
}

// ============================================================================
// Last-resort fallback: fully-fused kernel (used if ws_size is too small)
// ============================================================================
__global__ __launch_bounds__(256)
void pct_fused(
    const float* __restrict__ sparse_xyz,
    const float* __restrict__ sparse_feats,
    const int* __restrict__ nei_inds,
    const float* __restrict__ dense_xyz,
    const float* __restrict__ dense_feats,
    const float* __restrict__ pe_w0, const float* __restrict__ pe_b0,
    const float* __restrict__ pe_g0, const float* __restrict__ pe_be0,
    const float* __restrict__ pe_w1, const float* __restrict__ pe_b1,
    const float* __restrict__ pe_g1, const float* __restrict__ pe_be1,
    const float* __restrict__ wn_w0, const float* __restrict__ wn_b0,
    const float* __restrict__ wn_g0, const float* __restrict__ wn_be0,
    const float* __restrict__ wn_w1, const float* __restrict__ wn_b1,
    const float* __restrict__ wn_g1, const float* __restrict__ wn_be1,
    const float* __restrict__ wn_w2, const float* __restrict__ wn_b2,
    const float* __restrict__ wn_g2, const float* __restrict__ wn_be2,
    const float* __restrict__ lin_w, const float* __restrict__ lin_b,
    const float* __restrict__ lin_g, const float* __restrict__ lin_be,
    float* __restrict__ out)
{
  __shared__ __align__(16) unsigned short feat_s[KNN][CF];
  __shared__ float wts_s[KNN][MM];
  __shared__ float loc_s[KNN][3];
  __shared__ int   nei_s[KNN];
  __shared__ __align__(16) unsigned short out_tile[CF*MM][8];

  const int t  = threadIdx.x;
  const int n0 = blockIdx.x * 8;
  const int k  = t >> 4;
  const int l  = t & 15;

#pragma unroll 1
  for (int p = 0; p < 8; ++p) {
    const int n = n0 + p;
    if (t < KNN) {
      int idx = nei_inds[n*KNN + t];
      nei_s[t] = idx;
      loc_s[t][0] = sparse_xyz[idx*3+0] - dense_xyz[n*3+0];
      loc_s[t][1] = sparse_xyz[idx*3+1] - dense_xyz[n*3+1];
      loc_s[t][2] = sparse_xyz[idx*3+2] - dense_xyz[n*3+2];
    }
    __syncthreads();
    {
      const int gk = t >> 4;
      const int c8 = (t & 15) * 8;
      const float* src = sparse_feats + (long)nei_s[gk]*CIN + c8;
      const float4 va = *(const float4*)(src);
      const float4 vb = *(const float4*)(src + 4);
      unsigned short* dst = &feat_s[gk][c8];
      dst[0] = f2bf(va.x); dst[1] = f2bf(va.y); dst[2] = f2bf(va.z); dst[3] = f2bf(va.w);
      dst[4] = f2bf(vb.x); dst[5] = f2bf(vb.y); dst[6] = f2bf(vb.z); dst[7] = f2bf(vb.w);
    }
    const float x0 = loc_s[k][0], x1 = loc_s[k][1], x2 = loc_s[k][2];
    const int c0 = l, c1 = l + 16;
    float ha = x0*pe_w0[0*PEC+c0] + x1*pe_w0[1*PEC+c0] + x2*pe_w0[2*PEC+c0] + pe_b0[c0];
    float hb = x0*pe_w0[0*PEC+c1] + x1*pe_w0[1*PEC+c1] + x2*pe_w0[2*PEC+c1] + pe_b0[c1];
    {
      float mu = rsum16(ha + hb) * (1.f/32.f);
      float da = ha - mu, db = hb - mu;
      float q  = rsum16(da*da + db*db);
      float rs = rsqrtf(q*(1.f/32.f) + LEPS);
      ha = lrelu(da*rs*pe_g0[c0] + pe_be0[c0]);
      hb = lrelu(db*rs*pe_g0[c1] + pe_be0[c1]);
    }
    float za = pe_b1[c0], zb = pe_b1[c1];
#pragma unroll
    for (int j = 0; j < 16; ++j) {
      float va = __shfl(ha, j, 16);
      float vb = __shfl(hb, j, 16);
      za += va * pe_w1[j*PEC + c0] + vb * pe_w1[(j+16)*PEC + c0];
      zb += va * pe_w1[j*PEC + c1] + vb * pe_w1[(j+16)*PEC + c1];
    }
    {
      float mu = rsum16(za + zb) * (1.f/32.f);
      float da = za - mu, db = zb - mu;
      float q  = rsum16(da*da + db*db);
      float rs = rsqrtf(q*(1.f/32.f) + LEPS);
      feat_s[k][CIN + c0] = f2bf(da*rs*pe_g1[c0] + pe_be1[c0]);
      feat_s[k][CIN + c1] = f2bf(db*rs*pe_g1[c1] + pe_be1[c1]);
    }
    float w0v = x0*wn_w0[0*MM+l] + x1*wn_w0[1*MM+l] + x2*wn_w0[2*MM+l] + wn_b0[l];
    {
      float mu = rsum16(w0v) * (1.f/16.f);
      float d  = w0v - mu;
      float rs = rsqrtf(rsum16(d*d)*(1.f/16.f) + LEPS);
      w0v = lrelu(d*rs*wn_g0[l] + wn_be0[l]);
    }
    float w1v = wn_b1[l];
#pragma unroll
    for (int j = 0; j < 16; ++j)
      w1v += __shfl(w0v, j, 16) * wn_w1[j*MM + l];
    {
      float mu = rsum16(w1v) * (1.f/16.f);
      float d  = w1v - mu;
      float rs = rsqrtf(rsum16(d*d)*(1.f/16.f) + LEPS);
      w1v = lrelu(d*rs*wn_g1[l] + wn_be1[l]);
    }
    float w2v = wn_b2[l];
#pragma unroll
    for (int j = 0; j < 16; ++j)
      w2v += __shfl(w1v, j, 16) * wn_w2[j*MM + l];
    {
      float mu = rsum16(w2v) * (1.f/16.f);
      float d  = w2v - mu;
      float rs = rsqrtf(rsum16(d*d)*(1.f/16.f) + LEPS);
      w2v = d*rs*wn_g2[l] + wn_be2[l];
    }
    wts_s[k][l] = w2v;
    __syncthreads();
    {
      const int m = t & 15;
      const int g = t >> 4;
      float wv[KNN];
#pragma unroll
      for (int kk = 0; kk < KNN; ++kk) wv[kk] = wts_s[kk][m];
#pragma unroll
      for (int j = 0; j < 10; ++j) {
        const int c = g*10 + j;
        float acc = 0.f;
#pragma unroll
        for (int kk = 0; kk < KNN; ++kk)
          acc += bf2f(feat_s[kk][c]) * wv[kk];
        out_tile[c*MM + m][p] = f2bf(acc);
      }
    }
    __syncthreads();
  }
  {
    const int h  = t >> 6;
    const int o0 = (t & 63) * 2;
    float acc0[8], acc1[8];
#pragma unroll
    for (int p = 0; p < 8; ++p) { acc0[p] = 0.f; acc1[p] = 0.f; }
    const int i0 = h * 640;
    for (int i = i0; i < i0 + 640; ++i) {
      const float2 wv = *(const float2*)(lin_w + (long)i*COUT + o0);
      const float wa = wv.x;
      const float wc = wv.y;
      const uint4 r = *(const uint4*)(&out_tile[i][0]);
      const float f0 = bf2f((unsigned short)(r.x & 0xffffu));
      const float f1 = bf2f((unsigned short)(r.x >> 16));
      const float g2 = bf2f((unsigned short)(r.y & 0xffffu));
      const float g3 = bf2f((unsigned short)(r.y >> 16));
      const float g4 = bf2f((unsigned short)(r.z & 0xffffu));
      const float g5 = bf2f((unsigned short)(r.z >> 16));
      const float g6 = bf2f((unsigned short)(r.w & 0xffffu));
      const float g7 = bf2f((unsigned short)(r.w >> 16));
      acc0[0] += f0*wa; acc1[0] += f0*wc;
      acc0[1] += f1*wa; acc1[1] += f1*wc;
      acc0[2] += g2*wa; acc1[2] += g2*wc;
      acc0[3] += g3*wa; acc1[3] += g3*wc;
      acc0[4] += g4*wa; acc1[4] += g4*wc;
      acc0[5] += g5*wa; acc1[5] += g5*wc;
      acc0[6] += g6*wa; acc1[6] += g6*wc;
      acc0[7] += g7*wa; acc1[7] += g7*wc;
    }
    __syncthreads();
    float* red = (float*)&out_tile[0][0];
#pragma unroll
    for (int p = 0; p < 8; ++p) {
      red[((h*8 + p) << 7) + o0    ] = acc0[p];
      red[((h*8 + p) << 7) + o0 + 1] = acc1[p];
    }
    __syncthreads();
    const int p2 = t >> 5, l2 = t & 31;
    const int n  = n0 + p2;
    float v[4];
#pragma unroll
    for (int j = 0; j < 4; ++j) {
      const int o = l2 + (j << 5);
      float sv = red[((0*8 + p2) << 7) + o] + red[((1*8 + p2) << 7) + o]
               + red[((2*8 + p2) << 7) + o] + red[((3*8 + p2) << 7) + o];
      v[j] = sv + lin_b[o];
    }
    float mu = rsum32(v[0] + v[1] + v[2] + v[3]) * (1.f/128.f);
    float q = 0.f;
#pragma unroll
    for (int j = 0; j < 4; ++j) { float d = v[j] - mu; q += d*d; }
    float rs = rsqrtf(rsum32(q) * (1.f/128.f) + LEPS);
#pragma unroll
    for (int j = 0; j < 4; ++j) {
      const int o = l2 + (j << 5);
      float y = (v[j] - mu) * rs * lin_g[o] + lin_be[o];
      y = lrelu(y);
      y += dense_feats[n*COUT + o];
      out[n*COUT + o] = y;
    }
  }
}

extern "C" void kernel_launch(void* const* d_in, const int* in_sizes, int n_in,
                              void* d_out, int out_size, void* d_ws, size_t ws_size,
                              hipStream_t stream) {
  const int Nd = in_sizes[2] / KNN;    // 40000
  const int Ns = in_sizes[1] / CIN;    // 10000
  const size_t fr_bytes = (size_t)Nd * FRE * 2;        // 61.44 MB
  const size_t w_bytes  = (size_t)KDIM * COUT * 2;     // 655 KB
  const size_t f_bytes  = (size_t)Ns * CIN * 2;        // 2.56 MB
  const bool use_split = (ws_size >= fr_bytes + w_bytes + f_bytes)
                         && (Nd % NPB == 0) && ((Ns * CIN) % 4 == 0);

  if (use_split) {
    unsigned short* fragw = (unsigned short*)d_ws;
    unsigned short* wpack = (unsigned short*)((char*)d_ws + fr_bytes);
    unsigned short* sfb16 = (unsigned short*)((char*)d_ws + fr_bytes + w_bytes);

    const int n4 = Ns * CIN / 4;
    pct_prep<<<dim3(160 + (n4 + 255)/256), dim3(256), 0, stream>>>(
      (const float*)d_in[27], wpack, (const float*)d_in[1], sfb16, n4);

    pct_nets<<<dim3(Nd / NPB), dim3(256), 0, stream>>>(
      (const float*)d_in[0],  (const int*)d_in[2],  (const float*)d_in[4],
      (const float*)d_in[7],  (const float*)d_in[8],  (const float*)d_in[9],  (const float*)d_in[10],
      (const float*)d_in[11], (const float*)d_in[12], (const float*)d_in[13], (const float*)d_in[14],
      (const float*)d_in[15], (const float*)d_in[16], (const float*)d_in[17], (const float*)d_in[18],
      (const float*)d_in[19], (const float*)d_in[20], (const float*)d_in[21], (const float*)d_in[22],
      (const float*)d_in[23], (const float*)d_in[24], (const float*)d_in[25], (const float*)d_in[26],
      fragw);

    pct_eg<<<dim3(Nd / NPB), dim3(256), 0, stream>>>(
      (const int*)d_in[2], sfb16, fragw, wpack,
      (const float*)d_in[28], (const float*)d_in[29], (const float*)d_in[30],
      (const float*)d_in[6], (float*)d_out);
  } else {
    pct_fused<<<dim3(Nd / 8), dim3(256), 0, stream>>>(
      (const float*)d_in[0],  (const float*)d_in[1],  (const int*)d_in[2],
      (const float*)d_in[4],  (const float*)d_in[6],
      (const float*)d_in[7],  (const float*)d_in[8],  (const float*)d_in[9],  (const float*)d_in[10],
      (const float*)d_in[11], (const float*)d_in[12], (const float*)d_in[13], (const float*)d_in[14],
      (const float*)d_in[15], (const float*)d_in[16], (const float*)d_in[17], (const float*)d_in[18],
      (const float*)d_in[19], (const float*)d_in[20], (const float*)d_in[21], (const float*)d_in[22],
      (const float*)d_in[23], (const float*)d_in[24], (const float*)d_in[25], (const float*)d_in[26],
      (const float*)d_in[27], (const float*)d_in[28], (const float*)d_in[29], (const float*)d_in[30],
      (float*)d_out);
  }
}